// Round 1
// baseline (1158.962 us; speedup 1.0000x reference)
//
#include <hip/hip_runtime.h>

#define NS_N 10000
#define NM_N 50000
#define HD 128
#define E1_N 600000
#define E2_N 400000
#define L_N 200000

// ---------------- utility kernels ----------------

__global__ void zero_ints(int* __restrict__ p, int n) {
    int i = blockIdx.x * blockDim.x + threadIdx.x;
    if (i < n) p[i] = 0;
}

__global__ void count_edges(const int* __restrict__ s2m_src, const int* __restrict__ s2m_dst,
                            const int* __restrict__ sim_src, const int* __restrict__ sim_dst,
                            int* cntM, int* cntS, int* cnt0, int* cnt1) {
    int i = blockIdx.x * blockDim.x + threadIdx.x;
    int stride = gridDim.x * blockDim.x;
    for (int e = i; e < E1_N; e += stride) {
        atomicAdd(&cntM[s2m_dst[e]], 1);
        atomicAdd(&cntS[s2m_src[e]], 1);
    }
    for (int e = i; e < E2_N; e += stride) {
        atomicAdd(&cnt0[sim_dst[e]], 1);
        atomicAdd(&cnt1[sim_src[e]], 1);
    }
}

// 4 blocks; block b exclusive-scans array b into off and cur.
__global__ __launch_bounds__(1024) void scan4(
        const int* cntM, const int* cntS, const int* cnt0, const int* cnt1,
        int* offM, int* offS, int* off0, int* off1,
        int* curM, int* curS, int* cur0, int* cur1) {
    const int* cnt; int* off; int* cur; int n;
    switch (blockIdx.x) {
        case 0: cnt = cntM; off = offM; cur = curM; n = NM_N; break;
        case 1: cnt = cntS; off = offS; cur = curS; n = NS_N; break;
        case 2: cnt = cnt0; off = off0; cur = cur0; n = NM_N; break;
        default: cnt = cnt1; off = off1; cur = cur1; n = NM_N; break;
    }
    __shared__ int wsum[16];
    int tid = threadIdx.x, lane = tid & 63, w = tid >> 6;
    int carry = 0;
    for (int base = 0; base < n; base += 1024) {
        int idx = base + tid;
        int v = (idx < n) ? cnt[idx] : 0;
        int x = v;
        #pragma unroll
        for (int d = 1; d < 64; d <<= 1) {
            int y = __shfl_up(x, d);
            if (lane >= d) x += y;
        }
        if (lane == 63) wsum[w] = x;
        __syncthreads();
        if (w == 0) {
            int y = (lane < 16) ? wsum[lane] : 0;
            #pragma unroll
            for (int d = 1; d < 16; d <<= 1) {
                int z = __shfl_up(y, d);
                if (lane >= d) y += z;
            }
            if (lane < 16) wsum[lane] = y;
        }
        __syncthreads();
        int woff = (w > 0) ? wsum[w - 1] : 0;
        int excl = carry + woff + (x - v);
        if (idx < n) { off[idx] = excl; cur[idx] = excl; }
        int tot = wsum[15];
        __syncthreads();
        carry += tot;
    }
}

__global__ void place_edges(const int* __restrict__ s2m_src, const int* __restrict__ s2m_dst,
                            const int* __restrict__ sim_src, const int* __restrict__ sim_dst,
                            int* curM, int* curS, int* cur0, int* cur1,
                            int* csrA, int* csrS, int* csr0, int* csr1) {
    int i = blockIdx.x * blockDim.x + threadIdx.x;
    int stride = gridDim.x * blockDim.x;
    for (int e = i; e < E1_N; e += stride) {
        int s = s2m_src[e], d = s2m_dst[e];
        csrA[atomicAdd(&curM[d], 1)] = s;
        csrS[atomicAdd(&curS[s], 1)] = d;
    }
    for (int e = i; e < E2_N; e += stride) {
        int s = sim_src[e], d = sim_dst[e];
        csr0[atomicAdd(&cur0[d], 1)] = s;
        csr1[atomicAdd(&cur1[s], 1)] = d;
    }
}

__global__ void finalize(const int* cntM, const int* cntS, const int* cnt0, const int* cnt1,
                         float* invCntM, float* invCntS,
                         float* dinv0, float* inv0, float* dinv1, float* inv1,
                         const float* __restrict__ sage_bl, const float* __restrict__ gcn_b,
                         float* bsum) {
    int i = blockIdx.x * blockDim.x + threadIdx.x;
    if (i < NM_N) {
        int c = cntM[i];
        invCntM[i] = 1.0f / (float)(c > 1 ? c : 1);
        float d0 = (float)cnt0[i] + 1.0f;
        dinv0[i] = 1.0f / sqrtf(d0);
        inv0[i] = 1.0f / d0;
        float d1 = (float)cnt1[i] + 1.0f;
        dinv1[i] = 1.0f / sqrtf(d1);
        inv1[i] = 1.0f / d1;
    }
    if (i < NS_N) {
        int c = cntS[i];
        invCntS[i] = 1.0f / (float)(c > 1 ? c : 1);
    }
    if (i < 256) {
        int l = i >> 7, c = i & 127;
        bsum[i] = sage_bl[(l * 2 + 0) * HD + c] + gcn_b[(l * 2 + 0) * HD + c] + gcn_b[(l * 2 + 1) * HD + c];
    }
}

// ---------------- gather (CSR) aggregation ----------------
// one 32-lane half-wave per destination row, float4 per lane covers H=128

__global__ __launch_bounds__(256) void gather_mean(
        const float* __restrict__ x, const int* __restrict__ csr,
        const int* __restrict__ off, const int* __restrict__ cnt,
        const float* __restrict__ invc, float* __restrict__ out, int nrows) {
    int row = blockIdx.x * 8 + (threadIdx.x >> 5);
    if (row >= nrows) return;
    int lane = threadIdx.x & 31;
    int o = off[row], n = cnt[row];
    const float4* xv = (const float4*)x;
    float ax = 0.f, ay = 0.f, az = 0.f, aw = 0.f;
    int j = 0;
    for (; j + 2 <= n; j += 2) {
        int sa = csr[o + j], sb = csr[o + j + 1];
        float4 va = xv[(size_t)sa * 32 + lane];
        float4 vb = xv[(size_t)sb * 32 + lane];
        ax += va.x + vb.x; ay += va.y + vb.y; az += va.z + vb.z; aw += va.w + vb.w;
    }
    if (j < n) {
        int sa = csr[o + j];
        float4 va = xv[(size_t)sa * 32 + lane];
        ax += va.x; ay += va.y; az += va.z; aw += va.w;
    }
    float sc = invc[row];
    float4 r; r.x = ax * sc; r.y = ay * sc; r.z = az * sc; r.w = aw * sc;
    ((float4*)out)[(size_t)row * 32 + lane] = r;
}

__global__ __launch_bounds__(256) void gather_gcn(
        const float* __restrict__ x, const int* __restrict__ csr,
        const int* __restrict__ off, const int* __restrict__ cnt,
        const float* __restrict__ dinv, const float* __restrict__ invd,
        float* __restrict__ out, int nrows) {
    int row = blockIdx.x * 8 + (threadIdx.x >> 5);
    if (row >= nrows) return;
    int lane = threadIdx.x & 31;
    int o = off[row], n = cnt[row];
    const float4* xv = (const float4*)x;
    float ax = 0.f, ay = 0.f, az = 0.f, aw = 0.f;
    int j = 0;
    for (; j + 2 <= n; j += 2) {
        int sa = csr[o + j], sb = csr[o + j + 1];
        float ca = dinv[sa], cb = dinv[sb];
        float4 va = xv[(size_t)sa * 32 + lane];
        float4 vb = xv[(size_t)sb * 32 + lane];
        ax += ca * va.x + cb * vb.x; ay += ca * va.y + cb * vb.y;
        az += ca * va.z + cb * vb.z; aw += ca * va.w + cb * vb.w;
    }
    if (j < n) {
        int sa = csr[o + j];
        float ca = dinv[sa];
        float4 va = xv[(size_t)sa * 32 + lane];
        ax += ca * va.x; ay += ca * va.y; az += ca * va.z; aw += ca * va.w;
    }
    float dr = dinv[row], iv = invd[row];
    float4 self = xv[(size_t)row * 32 + lane];
    float4 r;
    r.x = dr * ax + iv * self.x; r.y = dr * ay + iv * self.y;
    r.z = dr * az + iv * self.z; r.w = dr * aw + iv * self.w;
    ((float4*)out)[(size_t)row * 32 + lane] = r;
}

// ---------------- fused multi-segment GEMM ----------------
// out[r][c] = relu(bias[c] + sum_s in_s[r][:] @ W_s[:][c]), 64 rows x 128 cols per block.
// LDS holds the 64x128 input tile transposed (k-major) with XOR swizzle so
// staging writes spread banks; compute reads are wave-uniform (broadcast, free).

__global__ __launch_bounds__(256) void gemm_fused(
        const float* __restrict__ in0, const float* __restrict__ in1,
        const float* __restrict__ in2, const float* __restrict__ in3,
        const float* __restrict__ w0, const float* __restrict__ w1,
        const float* __restrict__ w2, const float* __restrict__ w3,
        const float* __restrict__ bias, float* __restrict__ out,
        int nrows, int nseg) {
    __shared__ float xs[128 * 64];
    int tid = threadIdx.x;
    int c = tid & 127, g = tid >> 7;        // g: row-half selector (0/1)
    int r0 = blockIdx.x * 64;
    float acc[32];
    float b = bias[c];
    #pragma unroll
    for (int i = 0; i < 32; i++) acc[i] = b;

    for (int s = 0; s < nseg; s++) {
        const float* in; const float* W;
        switch (s) {
            case 0: in = in0; W = w0; break;
            case 1: in = in1; W = w1; break;
            case 2: in = in2; W = w2; break;
            default: in = in3; W = w3; break;
        }
        __syncthreads();   // protect previous k-loop reads before restaging
        // stage 64 rows x 128 k, transposed, swizzled
        #pragma unroll
        for (int rep = 0; rep < 8; rep++) {
            int f = rep * 256 + tid;     // 0..2047 float4 id
            int r = f >> 5;              // 0..63
            int k4 = f & 31;             // float4 index along k
            int grow = r0 + r;
            float4 v = (grow < nrows) ? ((const float4*)in)[(size_t)grow * 32 + k4]
                                      : make_float4(0.f, 0.f, 0.f, 0.f);
            int swz = (k4 & 7) << 2;
            int rr = r ^ swz;
            int kb = k4 * 4;
            xs[(kb + 0) * 64 + rr] = v.x;
            xs[(kb + 1) * 64 + rr] = v.y;
            xs[(kb + 2) * 64 + rr] = v.z;
            xs[(kb + 3) * 64 + rr] = v.w;
        }
        __syncthreads();
        #pragma unroll 4
        for (int k = 0; k < 128; k++) {
            float w = W[k * 128 + c];
            int swz = ((k >> 2) & 7) << 2;
            #pragma unroll
            for (int rg = 0; rg < 8; rg++) {
                float4 xvv = *(const float4*)&xs[k * 64 + ((g * 32 + rg * 4) ^ swz)];
                acc[rg * 4 + 0] += xvv.x * w;
                acc[rg * 4 + 1] += xvv.y * w;
                acc[rg * 4 + 2] += xvv.z * w;
                acc[rg * 4 + 3] += xvv.w * w;
            }
        }
    }
    #pragma unroll
    for (int i = 0; i < 32; i++) {
        int grow = r0 + g * 32 + i;
        if (grow < nrows) out[(size_t)grow * 128 + c] = fmaxf(acc[i], 0.f);
    }
}

// ---------------- classifier ----------------

__global__ __launch_bounds__(256) void classify(
        const float* __restrict__ xs_, const float* __restrict__ xm_,
        const int* __restrict__ lsrc, const int* __restrict__ ldst,
        float* __restrict__ out) {
    int i = blockIdx.x * 4 + (threadIdx.x >> 6);
    if (i >= L_N) return;
    int lane = threadIdx.x & 63;
    int s = lsrc[i], d = ldst[i];
    float2 a = ((const float2*)xs_)[(size_t)s * 64 + lane];
    float2 bm = ((const float2*)xm_)[(size_t)d * 64 + lane];
    float p = a.x * bm.x + a.y * bm.y;
    #pragma unroll
    for (int o = 32; o > 0; o >>= 1) p += __shfl_down(p, o);
    if (lane == 0) out[i] = p;
}

// ---------------- launch ----------------

extern "C" void kernel_launch(void* const* d_in, const int* in_sizes, int n_in,
                              void* d_out, int out_size, void* d_ws, size_t ws_size,
                              hipStream_t stream) {
    const float* emb_s   = (const float*)d_in[0];
    const float* emb_m   = (const float*)d_in[1];
    const float* sage_Wl = (const float*)d_in[2];
    const float* sage_bl = (const float*)d_in[3];
    const float* sage_Wr = (const float*)d_in[4];
    const float* gcn_W   = (const float*)d_in[5];
    const float* gcn_b   = (const float*)d_in[6];
    // d_in[7], d_in[8] are arange node ids -> identity, ignored
    const int* e1s = (const int*)d_in[9];
    const int* e1d = (const int*)d_in[10];
    const int* e2s = (const int*)d_in[11];
    const int* e2d = (const int*)d_in[12];
    const int* ls  = (const int*)d_in[13];
    const int* ld  = (const int*)d_in[14];
    float* out = (float*)d_out;

    char* p = (char*)d_ws;
    auto alloc = [&](size_t bytes) -> void* {
        void* r = (void*)p;
        p += (bytes + 255) & ~(size_t)255;
        return r;
    };
    const int NCNT = NM_N * 3 + NS_N;
    int* cntblock = (int*)alloc((size_t)NCNT * 4);
    int* cntM = cntblock;
    int* cntS = cntM + NM_N;
    int* cnt0 = cntS + NS_N;
    int* cnt1 = cnt0 + NM_N;
    int* offM = (int*)alloc((size_t)NM_N * 4);
    int* offS = (int*)alloc((size_t)NS_N * 4);
    int* off0 = (int*)alloc((size_t)NM_N * 4);
    int* off1 = (int*)alloc((size_t)NM_N * 4);
    int* curM = (int*)alloc((size_t)NM_N * 4);
    int* curS = (int*)alloc((size_t)NS_N * 4);
    int* cur0 = (int*)alloc((size_t)NM_N * 4);
    int* cur1 = (int*)alloc((size_t)NM_N * 4);
    float* invCntM = (float*)alloc((size_t)NM_N * 4);
    float* invCntS = (float*)alloc((size_t)NS_N * 4);
    float* dinv0 = (float*)alloc((size_t)NM_N * 4);
    float* inv0  = (float*)alloc((size_t)NM_N * 4);
    float* dinv1 = (float*)alloc((size_t)NM_N * 4);
    float* inv1  = (float*)alloc((size_t)NM_N * 4);
    float* bsum  = (float*)alloc(256 * 4);
    int* csrA = (int*)alloc((size_t)E1_N * 4);
    int* csrS = (int*)alloc((size_t)E1_N * 4);
    int* csr0 = (int*)alloc((size_t)E2_N * 4);
    int* csr1 = (int*)alloc((size_t)E2_N * 4);
    float* A  = (float*)alloc((size_t)NM_N * HD * 4);
    float* B0 = (float*)alloc((size_t)NM_N * HD * 4);
    float* B1 = (float*)alloc((size_t)NM_N * HD * 4);
    float* Sg = (float*)alloc((size_t)NS_N * HD * 4);
    float* xma = (float*)alloc((size_t)NM_N * HD * 4);
    float* xsa = (float*)alloc((size_t)NS_N * HD * 4);

    zero_ints<<<(NCNT + 255) / 256, 256, 0, stream>>>(cntblock, NCNT);
    count_edges<<<2048, 256, 0, stream>>>(e1s, e1d, e2s, e2d, cntM, cntS, cnt0, cnt1);
    scan4<<<4, 1024, 0, stream>>>(cntM, cntS, cnt0, cnt1,
                                  offM, offS, off0, off1,
                                  curM, curS, cur0, cur1);
    place_edges<<<2048, 256, 0, stream>>>(e1s, e1d, e2s, e2d,
                                          curM, curS, cur0, cur1,
                                          csrA, csrS, csr0, csr1);
    finalize<<<(NM_N + 255) / 256, 256, 0, stream>>>(cntM, cntS, cnt0, cnt1,
                                                     invCntM, invCntS,
                                                     dinv0, inv0, dinv1, inv1,
                                                     sage_bl, gcn_b, bsum);

    for (int l = 0; l < 2; l++) {
        const float* xs_cur = l ? (const float*)xsa : emb_s;
        const float* xm_cur = l ? (const float*)xma : emb_m;
        gather_mean<<<(NM_N + 7) / 8, 256, 0, stream>>>(xs_cur, csrA, offM, cntM, invCntM, A, NM_N);
        gather_mean<<<(NS_N + 7) / 8, 256, 0, stream>>>(xm_cur, csrS, offS, cntS, invCntS, Sg, NS_N);
        gather_gcn<<<(NM_N + 7) / 8, 256, 0, stream>>>(xm_cur, csr0, off0, cnt0, dinv0, inv0, B0, NM_N);
        gather_gcn<<<(NM_N + 7) / 8, 256, 0, stream>>>(xm_cur, csr1, off1, cnt1, dinv1, inv1, B1, NM_N);
        gemm_fused<<<(NM_N + 63) / 64, 256, 0, stream>>>(
            A, xm_cur, B0, B1,
            sage_Wl + (size_t)(l * 2 + 0) * HD * HD,
            sage_Wr + (size_t)(l * 2 + 0) * HD * HD,
            gcn_W + (size_t)(l * 2 + 0) * HD * HD,
            gcn_W + (size_t)(l * 2 + 1) * HD * HD,
            bsum + l * 128, xma, NM_N, 4);
        gemm_fused<<<(NS_N + 63) / 64, 256, 0, stream>>>(
            Sg, xs_cur, nullptr, nullptr,
            sage_Wl + (size_t)(l * 2 + 1) * HD * HD,
            sage_Wr + (size_t)(l * 2 + 1) * HD * HD,
            nullptr, nullptr,
            sage_bl + (size_t)(l * 2 + 1) * HD, xsa, NS_N, 2);
    }
    classify<<<(L_N + 3) / 4, 256, 0, stream>>>(xsa, xma, ls, ld, out);
}

// Round 2
// 757.284 us; speedup vs baseline: 1.5304x; 1.5304x over previous
//
#include <hip/hip_runtime.h>

#define NS_N 10000
#define NM_N 50000
#define HD 128
#define E1_N 600000
#define E2_N 400000
#define L_N 200000

typedef short bf16x8 __attribute__((ext_vector_type(8)));
typedef float f32x4 __attribute__((ext_vector_type(4)));

__device__ inline float bf2f(unsigned int h) {
    union { unsigned int u; float f; } c; c.u = h << 16; return c.f;
}
__device__ inline unsigned short f2bf(float f) {
    union { float f; unsigned int u; } c; c.f = f;
    return (unsigned short)((c.u + 0x7fffu + ((c.u >> 16) & 1u)) >> 16);
}

// ---------------- utility kernels ----------------

__global__ void zero_ints(int* __restrict__ p, int n) {
    int i = blockIdx.x * blockDim.x + threadIdx.x;
    if (i < n) p[i] = 0;
}

__global__ void count_edges(const int* __restrict__ s2m_src, const int* __restrict__ s2m_dst,
                            const int* __restrict__ sim_src, const int* __restrict__ sim_dst,
                            int* cntM, int* cntS, int* cnt0, int* cnt1) {
    int i = blockIdx.x * blockDim.x + threadIdx.x;
    int stride = gridDim.x * blockDim.x;
    for (int e = i; e < E1_N; e += stride) {
        atomicAdd(&cntM[s2m_dst[e]], 1);
        atomicAdd(&cntS[s2m_src[e]], 1);
    }
    for (int e = i; e < E2_N; e += stride) {
        atomicAdd(&cnt0[sim_dst[e]], 1);
        atomicAdd(&cnt1[sim_src[e]], 1);
    }
}

__global__ __launch_bounds__(1024) void scan4(
        const int* cntM, const int* cntS, const int* cnt0, const int* cnt1,
        int* offM, int* offS, int* off0, int* off1,
        int* curM, int* curS, int* cur0, int* cur1) {
    const int* cnt; int* off; int* cur; int n;
    switch (blockIdx.x) {
        case 0: cnt = cntM; off = offM; cur = curM; n = NM_N; break;
        case 1: cnt = cntS; off = offS; cur = curS; n = NS_N; break;
        case 2: cnt = cnt0; off = off0; cur = cur0; n = NM_N; break;
        default: cnt = cnt1; off = off1; cur = cur1; n = NM_N; break;
    }
    __shared__ int wsum[16];
    int tid = threadIdx.x, lane = tid & 63, w = tid >> 6;
    int carry = 0;
    for (int base = 0; base < n; base += 1024) {
        int idx = base + tid;
        int v = (idx < n) ? cnt[idx] : 0;
        int x = v;
        #pragma unroll
        for (int d = 1; d < 64; d <<= 1) {
            int y = __shfl_up(x, d);
            if (lane >= d) x += y;
        }
        if (lane == 63) wsum[w] = x;
        __syncthreads();
        if (w == 0) {
            int y = (lane < 16) ? wsum[lane] : 0;
            #pragma unroll
            for (int d = 1; d < 16; d <<= 1) {
                int z = __shfl_up(y, d);
                if (lane >= d) y += z;
            }
            if (lane < 16) wsum[lane] = y;
        }
        __syncthreads();
        int woff = (w > 0) ? wsum[w - 1] : 0;
        int excl = carry + woff + (x - v);
        if (idx < n) { off[idx] = excl; cur[idx] = excl; }
        int tot = wsum[15];
        __syncthreads();
        carry += tot;
    }
}

__global__ void place_edges(const int* __restrict__ s2m_src, const int* __restrict__ s2m_dst,
                            const int* __restrict__ sim_src, const int* __restrict__ sim_dst,
                            int* curM, int* curS, int* cur0, int* cur1,
                            int* csrA, int* csrS, int* csr0, int* csr1) {
    int i = blockIdx.x * blockDim.x + threadIdx.x;
    int stride = gridDim.x * blockDim.x;
    for (int e = i; e < E1_N; e += stride) {
        int s = s2m_src[e], d = s2m_dst[e];
        csrA[atomicAdd(&curM[d], 1)] = s;
        csrS[atomicAdd(&curS[s], 1)] = d;
    }
    for (int e = i; e < E2_N; e += stride) {
        int s = sim_src[e], d = sim_dst[e];
        csr0[atomicAdd(&cur0[d], 1)] = s;
        csr1[atomicAdd(&cur1[s], 1)] = d;
    }
}

__global__ void finalize(const int* cntM, const int* cntS, const int* cnt0, const int* cnt1,
                         float* invCntM, float* invCntS,
                         float* dinv0, float* inv0, float* dinv1, float* inv1,
                         const float* __restrict__ sage_bl, const float* __restrict__ gcn_b,
                         float* bsum) {
    int i = blockIdx.x * blockDim.x + threadIdx.x;
    if (i < NM_N) {
        int c = cntM[i];
        invCntM[i] = 1.0f / (float)(c > 1 ? c : 1);
        float d0 = (float)cnt0[i] + 1.0f;
        dinv0[i] = 1.0f / sqrtf(d0);
        inv0[i] = 1.0f / d0;
        float d1 = (float)cnt1[i] + 1.0f;
        dinv1[i] = 1.0f / sqrtf(d1);
        inv1[i] = 1.0f / d1;
    }
    if (i < NS_N) {
        int c = cntS[i];
        invCntS[i] = 1.0f / (float)(c > 1 ? c : 1);
    }
    if (i < 256) {
        int l = i >> 7, c = i & 127;
        bsum[i] = sage_bl[(l * 2 + 0) * HD + c] + gcn_b[(l * 2 + 0) * HD + c] + gcn_b[(l * 2 + 1) * HD + c];
    }
}

// ---------------- fp32 -> bf16 conversions ----------------

__global__ void conv_f32_bf16(const float* __restrict__ src, unsigned short* __restrict__ dst, int n8) {
    int i = blockIdx.x * blockDim.x + threadIdx.x;
    int stride = gridDim.x * blockDim.x;
    for (; i < n8; i += stride) {
        float4 v0 = ((const float4*)src)[(size_t)i * 2];
        float4 v1 = ((const float4*)src)[(size_t)i * 2 + 1];
        uint4 r;
        r.x = (unsigned int)f2bf(v0.x) | ((unsigned int)f2bf(v0.y) << 16);
        r.y = (unsigned int)f2bf(v0.z) | ((unsigned int)f2bf(v0.w) << 16);
        r.z = (unsigned int)f2bf(v1.x) | ((unsigned int)f2bf(v1.y) << 16);
        r.w = (unsigned int)f2bf(v1.z) | ((unsigned int)f2bf(v1.w) << 16);
        ((uint4*)dst)[i] = r;
    }
}

// Wt[o][n][k] (bf16, transposed) for o = l*6 + m:
//  m 0..3 : M-gemm segs {sage_Wl[l,0], sage_Wr[l,0], gcn_W[l,0], gcn_W[l,1]}
//  m 4..5 : S-gemm segs {sage_Wl[l,1], sage_Wr[l,1]}
__global__ __launch_bounds__(256) void conv_w(const float* __restrict__ sage_Wl,
                                              const float* __restrict__ sage_Wr,
                                              const float* __restrict__ gcn_W,
                                              unsigned short* __restrict__ Wt) {
    int o = blockIdx.x;
    int l = o / 6, m = o % 6;
    const float* src;
    switch (m) {
        case 0: src = sage_Wl + (size_t)(l * 2 + 0) * HD * HD; break;
        case 1: src = sage_Wr + (size_t)(l * 2 + 0) * HD * HD; break;
        case 2: src = gcn_W + (size_t)(l * 2 + 0) * HD * HD; break;
        case 3: src = gcn_W + (size_t)(l * 2 + 1) * HD * HD; break;
        case 4: src = sage_Wl + (size_t)(l * 2 + 1) * HD * HD; break;
        default: src = sage_Wr + (size_t)(l * 2 + 1) * HD * HD; break;
    }
    for (int it = 0; it < 64; it++) {
        int f = it * 256 + threadIdx.x;      // f = n*128 + k
        int n = f >> 7, k = f & 127;
        Wt[(size_t)o * 16384 + f] = f2bf(src[k * 128 + n]);
    }
}

// ---------------- gather (CSR) aggregation, bf16 in/out, fp32 accum ----------------
// 16 lanes per destination row (row = 128 bf16 = 16 lanes x 16B)

__global__ __launch_bounds__(256) void gather_mean16(
        const unsigned short* __restrict__ x, const int* __restrict__ csr,
        const int* __restrict__ off, const int* __restrict__ cnt,
        const float* __restrict__ invc, unsigned short* __restrict__ out, int nrows) {
    int row = blockIdx.x * 16 + (threadIdx.x >> 4);
    if (row >= nrows) return;
    int lane = threadIdx.x & 15;
    int o = off[row], n = cnt[row];
    float a0=0,a1=0,a2=0,a3=0,a4=0,a5=0,a6=0,a7=0;
    for (int j = 0; j < n; j++) {
        int s = csr[o + j];
        uint4 v = *(const uint4*)(x + (size_t)s * 128 + lane * 8);
        a0 += bf2f(v.x & 0xffffu); a1 += bf2f(v.x >> 16);
        a2 += bf2f(v.y & 0xffffu); a3 += bf2f(v.y >> 16);
        a4 += bf2f(v.z & 0xffffu); a5 += bf2f(v.z >> 16);
        a6 += bf2f(v.w & 0xffffu); a7 += bf2f(v.w >> 16);
    }
    float sc = invc[row];
    uint4 r;
    r.x = (unsigned int)f2bf(a0 * sc) | ((unsigned int)f2bf(a1 * sc) << 16);
    r.y = (unsigned int)f2bf(a2 * sc) | ((unsigned int)f2bf(a3 * sc) << 16);
    r.z = (unsigned int)f2bf(a4 * sc) | ((unsigned int)f2bf(a5 * sc) << 16);
    r.w = (unsigned int)f2bf(a6 * sc) | ((unsigned int)f2bf(a7 * sc) << 16);
    *(uint4*)(out + (size_t)row * 128 + lane * 8) = r;
}

__global__ __launch_bounds__(256) void gather_gcn16(
        const unsigned short* __restrict__ x, const int* __restrict__ csr,
        const int* __restrict__ off, const int* __restrict__ cnt,
        const float* __restrict__ dinv, const float* __restrict__ invd,
        unsigned short* __restrict__ out, int nrows) {
    int row = blockIdx.x * 16 + (threadIdx.x >> 4);
    if (row >= nrows) return;
    int lane = threadIdx.x & 15;
    int o = off[row], n = cnt[row];
    float a0=0,a1=0,a2=0,a3=0,a4=0,a5=0,a6=0,a7=0;
    for (int j = 0; j < n; j++) {
        int s = csr[o + j];
        float cf = dinv[s];
        uint4 v = *(const uint4*)(x + (size_t)s * 128 + lane * 8);
        a0 += cf * bf2f(v.x & 0xffffu); a1 += cf * bf2f(v.x >> 16);
        a2 += cf * bf2f(v.y & 0xffffu); a3 += cf * bf2f(v.y >> 16);
        a4 += cf * bf2f(v.z & 0xffffu); a5 += cf * bf2f(v.z >> 16);
        a6 += cf * bf2f(v.w & 0xffffu); a7 += cf * bf2f(v.w >> 16);
    }
    float dr = dinv[row], iv = invd[row];
    uint4 sv = *(const uint4*)(x + (size_t)row * 128 + lane * 8);
    uint4 r;
    r.x = (unsigned int)f2bf(dr * a0 + iv * bf2f(sv.x & 0xffffu)) |
          ((unsigned int)f2bf(dr * a1 + iv * bf2f(sv.x >> 16)) << 16);
    r.y = (unsigned int)f2bf(dr * a2 + iv * bf2f(sv.y & 0xffffu)) |
          ((unsigned int)f2bf(dr * a3 + iv * bf2f(sv.y >> 16)) << 16);
    r.z = (unsigned int)f2bf(dr * a4 + iv * bf2f(sv.z & 0xffffu)) |
          ((unsigned int)f2bf(dr * a5 + iv * bf2f(sv.z >> 16)) << 16);
    r.w = (unsigned int)f2bf(dr * a6 + iv * bf2f(sv.w & 0xffffu)) |
          ((unsigned int)f2bf(dr * a7 + iv * bf2f(sv.w >> 16)) << 16);
    *(uint4*)(out + (size_t)row * 128 + lane * 8) = r;
}

// ---------------- MFMA multi-segment GEMM ----------------
// 128x128 tile per block, 4 waves of 64x64, mfma_f32_16x16x32_bf16, fp32 acc.
// A: [row][k] bf16 in LDS, 16B chunks XOR-swizzled: chunk(row,c) = row*16 + (c ^ (row&7)).
// Wt: [n][k] bf16 (pre-transposed), same swizzle.

__global__ __launch_bounds__(256) void gemm_mfma(
        const unsigned short* __restrict__ in0, const unsigned short* __restrict__ in1,
        const unsigned short* __restrict__ in2, const unsigned short* __restrict__ in3,
        const unsigned short* __restrict__ Wt,   // [nseg][128][128]
        const float* __restrict__ bias, unsigned short* __restrict__ out,
        int nrows, int nseg) {
    __shared__ unsigned short As[128 * 128];
    __shared__ unsigned short Ws[128 * 128];
    int tid = threadIdx.x;
    int wid = tid >> 6, lane = tid & 63;
    int l16 = lane & 15, lhi = lane >> 4;
    int r0 = blockIdx.x * 128;
    int wr_ = (wid >> 1) * 64, wc_ = (wid & 1) * 64;
    f32x4 acc[4][4];
    #pragma unroll
    for (int i = 0; i < 4; i++)
        #pragma unroll
        for (int j = 0; j < 4; j++)
            acc[i][j] = (f32x4){0.f, 0.f, 0.f, 0.f};

    for (int s = 0; s < nseg; s++) {
        const unsigned short* in = (s == 0) ? in0 : (s == 1) ? in1 : (s == 2) ? in2 : in3;
        const unsigned short* W = Wt + (size_t)s * 16384;
        __syncthreads();
        #pragma unroll
        for (int it = 0; it < 8; it++) {
            int f = it * 256 + tid;      // 16B-chunk id: 128 rows x 16 chunks
            int r = f >> 4, c = f & 15;
            int gr = r0 + r;
            uint4 v = {0u, 0u, 0u, 0u};
            if (gr < nrows) v = *(const uint4*)(in + (size_t)gr * 128 + c * 8);
            *(uint4*)&As[(size_t)(r * 16 + (c ^ (r & 7))) * 8] = v;
            uint4 wv = *(const uint4*)(W + (size_t)r * 128 + c * 8);
            *(uint4*)&Ws[(size_t)(r * 16 + (c ^ (r & 7))) * 8] = wv;
        }
        __syncthreads();
        #pragma unroll
        for (int ks = 0; ks < 4; ks++) {
            int kc = ks * 4 + lhi;
            bf16x8 a[4], b[4];
            #pragma unroll
            for (int i = 0; i < 4; i++) {
                int r = wr_ + i * 16 + l16;
                a[i] = *(const bf16x8*)&As[(size_t)(r * 16 + (kc ^ (r & 7))) * 8];
                int nn = wc_ + i * 16 + l16;
                b[i] = *(const bf16x8*)&Ws[(size_t)(nn * 16 + (kc ^ (nn & 7))) * 8];
            }
            #pragma unroll
            for (int i = 0; i < 4; i++)
                #pragma unroll
                for (int j = 0; j < 4; j++)
                    acc[i][j] = __builtin_amdgcn_mfma_f32_16x16x32_bf16(a[i], b[j], acc[i][j], 0, 0, 0);
        }
    }
    float bs[4];
    #pragma unroll
    for (int j = 0; j < 4; j++) bs[j] = bias[wc_ + j * 16 + l16];
    #pragma unroll
    for (int i = 0; i < 4; i++) {
        int rb = r0 + wr_ + i * 16 + lhi * 4;
        #pragma unroll
        for (int j = 0; j < 4; j++) {
            int cn = wc_ + j * 16 + l16;
            #pragma unroll
            for (int q = 0; q < 4; q++) {
                int r = rb + q;
                if (r < nrows) {
                    float v = acc[i][j][q] + bs[j];
                    out[(size_t)r * 128 + cn] = f2bf(fmaxf(v, 0.f));
                }
            }
        }
    }
}

// ---------------- classifier ----------------

__global__ __launch_bounds__(256) void classify16(
        const unsigned short* __restrict__ xs_, const unsigned short* __restrict__ xm_,
        const int* __restrict__ lsrc, const int* __restrict__ ldst,
        float* __restrict__ out) {
    int i = blockIdx.x * 4 + (threadIdx.x >> 6);
    if (i >= L_N) return;
    int lane = threadIdx.x & 63;
    int s = lsrc[i], d = ldst[i];
    unsigned int a = *(const unsigned int*)(xs_ + (size_t)s * 128 + lane * 2);
    unsigned int b = *(const unsigned int*)(xm_ + (size_t)d * 128 + lane * 2);
    float p = bf2f(a & 0xffffu) * bf2f(b & 0xffffu) + bf2f(a >> 16) * bf2f(b >> 16);
    #pragma unroll
    for (int o = 32; o > 0; o >>= 1) p += __shfl_xor(p, o);
    if (lane == 0) out[i] = p;
}

// ---------------- launch ----------------

extern "C" void kernel_launch(void* const* d_in, const int* in_sizes, int n_in,
                              void* d_out, int out_size, void* d_ws, size_t ws_size,
                              hipStream_t stream) {
    const float* emb_s   = (const float*)d_in[0];
    const float* emb_m   = (const float*)d_in[1];
    const float* sage_Wl = (const float*)d_in[2];
    const float* sage_bl = (const float*)d_in[3];
    const float* sage_Wr = (const float*)d_in[4];
    const float* gcn_W   = (const float*)d_in[5];
    const float* gcn_b   = (const float*)d_in[6];
    const int* e1s = (const int*)d_in[9];
    const int* e1d = (const int*)d_in[10];
    const int* e2s = (const int*)d_in[11];
    const int* e2d = (const int*)d_in[12];
    const int* ls  = (const int*)d_in[13];
    const int* ld  = (const int*)d_in[14];
    float* out = (float*)d_out;

    char* p = (char*)d_ws;
    auto alloc = [&](size_t bytes) -> void* {
        void* r = (void*)p;
        p += (bytes + 255) & ~(size_t)255;
        return r;
    };
    const int NCNT = NM_N * 3 + NS_N;
    int* cntblock = (int*)alloc((size_t)NCNT * 4);
    int* cntM = cntblock;
    int* cntS = cntM + NM_N;
    int* cnt0 = cntS + NS_N;
    int* cnt1 = cnt0 + NM_N;
    int* offM = (int*)alloc((size_t)NM_N * 4);
    int* offS = (int*)alloc((size_t)NS_N * 4);
    int* off0 = (int*)alloc((size_t)NM_N * 4);
    int* off1 = (int*)alloc((size_t)NM_N * 4);
    int* curM = (int*)alloc((size_t)NM_N * 4);
    int* curS = (int*)alloc((size_t)NS_N * 4);
    int* cur0 = (int*)alloc((size_t)NM_N * 4);
    int* cur1 = (int*)alloc((size_t)NM_N * 4);
    float* invCntM = (float*)alloc((size_t)NM_N * 4);
    float* invCntS = (float*)alloc((size_t)NS_N * 4);
    float* dinv0 = (float*)alloc((size_t)NM_N * 4);
    float* inv0  = (float*)alloc((size_t)NM_N * 4);
    float* dinv1 = (float*)alloc((size_t)NM_N * 4);
    float* inv1  = (float*)alloc((size_t)NM_N * 4);
    float* bsum  = (float*)alloc(256 * 4);
    int* csrA = (int*)alloc((size_t)E1_N * 4);
    int* csrS = (int*)alloc((size_t)E1_N * 4);
    int* csr0 = (int*)alloc((size_t)E2_N * 4);
    int* csr1 = (int*)alloc((size_t)E2_N * 4);
    unsigned short* emb_s16 = (unsigned short*)alloc((size_t)NS_N * HD * 2);
    unsigned short* emb_m16 = (unsigned short*)alloc((size_t)NM_N * HD * 2);
    unsigned short* Wt  = (unsigned short*)alloc((size_t)12 * HD * HD * 2);
    unsigned short* A   = (unsigned short*)alloc((size_t)NM_N * HD * 2);
    unsigned short* B0  = (unsigned short*)alloc((size_t)NM_N * HD * 2);
    unsigned short* B1  = (unsigned short*)alloc((size_t)NM_N * HD * 2);
    unsigned short* Sg  = (unsigned short*)alloc((size_t)NS_N * HD * 2);
    unsigned short* xma = (unsigned short*)alloc((size_t)NM_N * HD * 2);
    unsigned short* xsa = (unsigned short*)alloc((size_t)NS_N * HD * 2);

    zero_ints<<<(NCNT + 255) / 256, 256, 0, stream>>>(cntblock, NCNT);
    count_edges<<<2048, 256, 0, stream>>>(e1s, e1d, e2s, e2d, cntM, cntS, cnt0, cnt1);
    scan4<<<4, 1024, 0, stream>>>(cntM, cntS, cnt0, cnt1,
                                  offM, offS, off0, off1,
                                  curM, curS, cur0, cur1);
    place_edges<<<2048, 256, 0, stream>>>(e1s, e1d, e2s, e2d,
                                          curM, curS, cur0, cur1,
                                          csrA, csrS, csr0, csr1);
    finalize<<<(NM_N + 255) / 256, 256, 0, stream>>>(cntM, cntS, cnt0, cnt1,
                                                     invCntM, invCntS,
                                                     dinv0, inv0, dinv1, inv1,
                                                     sage_bl, gcn_b, bsum);
    conv_f32_bf16<<<640, 256, 0, stream>>>(emb_s, emb_s16, NS_N * HD / 8);
    conv_f32_bf16<<<2048, 256, 0, stream>>>(emb_m, emb_m16, NM_N * HD / 8);
    conv_w<<<12, 256, 0, stream>>>(sage_Wl, sage_Wr, gcn_W, Wt);

    for (int l = 0; l < 2; l++) {
        const unsigned short* xs_cur = l ? (const unsigned short*)xsa : emb_s16;
        const unsigned short* xm_cur = l ? (const unsigned short*)xma : emb_m16;
        gather_mean16<<<(NM_N + 15) / 16, 256, 0, stream>>>(xs_cur, csrA, offM, cntM, invCntM, A, NM_N);
        gather_mean16<<<(NS_N + 15) / 16, 256, 0, stream>>>(xm_cur, csrS, offS, cntS, invCntS, Sg, NS_N);
        gather_gcn16<<<(NM_N + 15) / 16, 256, 0, stream>>>(xm_cur, csr0, off0, cnt0, dinv0, inv0, B0, NM_N);
        gather_gcn16<<<(NM_N + 15) / 16, 256, 0, stream>>>(xm_cur, csr1, off1, cnt1, dinv1, inv1, B1, NM_N);
        gemm_mfma<<<(NM_N + 127) / 128, 256, 0, stream>>>(
            A, xm_cur, B0, B1,
            Wt + (size_t)(l * 6) * HD * HD,
            bsum + l * 128, xma, NM_N, 4);
        gemm_mfma<<<(NS_N + 127) / 128, 256, 0, stream>>>(
            Sg, xs_cur, nullptr, nullptr,
            Wt + (size_t)(l * 6 + 4) * HD * HD,
            sage_bl + (size_t)(l * 2 + 1) * HD, xsa, NS_N, 2);
    }
    classify16<<<(L_N + 3) / 4, 256, 0, stream>>>(xsa, xma, ls, ld, out);
}

// Round 6
// 541.344 us; speedup vs baseline: 2.1409x; 1.3989x over previous
//
#include <hip/hip_runtime.h>

#define NS_N 10000
#define NM_N 50000
#define HD 128
#define E1_N 600000
#define E2_N 400000
#define L_N 200000

#define RSZ 4096
#define NB_A 13
#define NB_S 3
#define NB_0 13
#define NB_1 13
#define NB_TOT 42

typedef short bf16x8 __attribute__((ext_vector_type(8)));
typedef float f32x4 __attribute__((ext_vector_type(4)));

__device__ inline float bf2f(unsigned int h) {
    union { unsigned int u; float f; } c; c.u = h << 16; return c.f;
}
__device__ inline unsigned short f2bf(float f) {
    union { float f; unsigned int u; } c; c.f = f;
    return (unsigned short)((c.u + 0x7fffu + ((c.u >> 16) & 1u)) >> 16);
}

// ---------------- CSR build: range-partitioned, no global atomics ----------------
// block b owns a 4096-node range of one of the 4 CSRs:
//  [0,13): csrA  key=e1d payload=e1s  (s2m by dst, NM nodes)
//  [13,16): csrS key=e1s payload=e1d  (s2m by src, NS nodes)
//  [16,29): csr0 key=e2d payload=e2s  (sim by dst, NM nodes)
//  [29,42): csr1 key=e2s payload=e2d  (sim by src, NM nodes)

__global__ __launch_bounds__(1024) void count_ranges(
        const int* __restrict__ e1s, const int* __restrict__ e1d,
        const int* __restrict__ e2s, const int* __restrict__ e2d,
        int* cntM, int* cntS, int* cnt0, int* cnt1, int* rangeTot) {
    __shared__ int hist[RSZ];
    __shared__ int wred[16];
    int b = blockIdx.x, tid = threadIdx.x;
    const int* keys; int ne; int* cnt; int nnode; int r0;
    if (b < NB_A)            { keys = e1d; ne = E1_N; cnt = cntM; nnode = NM_N; r0 = b * RSZ; }
    else if (b < NB_A + NB_S){ keys = e1s; ne = E1_N; cnt = cntS; nnode = NS_N; r0 = (b - NB_A) * RSZ; }
    else if (b < 29)         { keys = e2d; ne = E2_N; cnt = cnt0; nnode = NM_N; r0 = (b - 16) * RSZ; }
    else                     { keys = e2s; ne = E2_N; cnt = cnt1; nnode = NM_N; r0 = (b - 29) * RSZ; }
    for (int i = tid; i < RSZ; i += 1024) hist[i] = 0;
    __syncthreads();
    int hi = nnode - r0; if (hi > RSZ) hi = RSZ;
    const int4* k4 = (const int4*)keys;
    int ne4 = ne >> 2;
    for (int i = tid; i < ne4; i += 1024) {
        int4 v = k4[i];
        int x;
        x = v.x - r0; if ((unsigned)x < (unsigned)hi) atomicAdd(&hist[x], 1);
        x = v.y - r0; if ((unsigned)x < (unsigned)hi) atomicAdd(&hist[x], 1);
        x = v.z - r0; if ((unsigned)x < (unsigned)hi) atomicAdd(&hist[x], 1);
        x = v.w - r0; if ((unsigned)x < (unsigned)hi) atomicAdd(&hist[x], 1);
    }
    __syncthreads();
    int loc = 0;
    for (int i = tid; i < hi; i += 1024) { int c = hist[i]; cnt[r0 + i] = c; loc += c; }
    #pragma unroll
    for (int o = 32; o; o >>= 1) loc += __shfl_xor(loc, o);
    if ((tid & 63) == 0) wred[tid >> 6] = loc;
    __syncthreads();
    if (tid == 0) {
        int t = 0;
        #pragma unroll
        for (int i = 0; i < 16; i++) t += wred[i];
        rangeTot[b] = t;
    }
}

__global__ void scan_ranges(const int* __restrict__ rangeTot, int* rangeBase) {
    int t = threadIdx.x;
    if (t >= 4) return;
    const int s0[5] = {0, 13, 16, 29, 42};
    int acc = 0;
    for (int i = s0[t]; i < s0[t + 1]; i++) { rangeBase[i] = acc; acc += rangeTot[i]; }
}

__global__ __launch_bounds__(1024) void place_ranges(
        const int* __restrict__ e1s, const int* __restrict__ e1d,
        const int* __restrict__ e2s, const int* __restrict__ e2d,
        const int* __restrict__ cntM, const int* __restrict__ cntS,
        const int* __restrict__ cnt0, const int* __restrict__ cnt1,
        const int* __restrict__ rangeBase,
        int* offM, int* offS, int* off0, int* off1,
        int* csrA, int* csrS, int* csr0, int* csr1) {
    __shared__ int cur[RSZ];
    __shared__ int wsum[16];
    int b = blockIdx.x, tid = threadIdx.x;
    int lane = tid & 63, w = tid >> 6;
    const int* keys; const int* payl; int ne; const int* cnt; int* off; int* csr; int nnode; int r0;
    if (b < NB_A)            { keys = e1d; payl = e1s; ne = E1_N; cnt = cntM; off = offM; csr = csrA; nnode = NM_N; r0 = b * RSZ; }
    else if (b < NB_A + NB_S){ keys = e1s; payl = e1d; ne = E1_N; cnt = cntS; off = offS; csr = csrS; nnode = NS_N; r0 = (b - NB_A) * RSZ; }
    else if (b < 29)         { keys = e2d; payl = e2s; ne = E2_N; cnt = cnt0; off = off0; csr = csr0; nnode = NM_N; r0 = (b - 16) * RSZ; }
    else                     { keys = e2s; payl = e2d; ne = E2_N; cnt = cnt1; off = off1; csr = csr1; nnode = NM_N; r0 = (b - 29) * RSZ; }
    int hi = nnode - r0; if (hi > RSZ) hi = RSZ;
    int base = rangeBase[b];
    // block exclusive scan of counts (4 per thread)
    int c[4]; int s = 0;
    #pragma unroll
    for (int q = 0; q < 4; q++) {
        int idx = tid * 4 + q;
        c[q] = (idx < hi) ? cnt[r0 + idx] : 0;
        s += c[q];
    }
    int x = s;
    #pragma unroll
    for (int d = 1; d < 64; d <<= 1) { int y = __shfl_up(x, d); if (lane >= d) x += y; }
    if (lane == 63) wsum[w] = x;
    __syncthreads();
    if (w == 0 && lane < 16) {
        int y = wsum[lane];
        #pragma unroll
        for (int d = 1; d < 16; d <<= 1) { int z = __shfl_up(y, d); if (lane >= d) y += z; }
        wsum[lane] = y;
    }
    __syncthreads();
    int ebase = base + ((w > 0) ? wsum[w - 1] : 0) + (x - s);
    #pragma unroll
    for (int q = 0; q < 4; q++) {
        int idx = tid * 4 + q;
        if (idx < hi) { cur[idx] = ebase; off[r0 + idx] = ebase; }
        ebase += c[q];
    }
    __syncthreads();
    // scatter edges of this range
    const int4* k4 = (const int4*)keys;
    const int4* p4 = (const int4*)payl;
    int ne4 = ne >> 2;
    for (int i = tid; i < ne4; i += 1024) {
        int4 k = k4[i]; int4 p = p4[i];
        int xx;
        xx = k.x - r0; if ((unsigned)xx < (unsigned)hi) csr[atomicAdd(&cur[xx], 1)] = p.x;
        xx = k.y - r0; if ((unsigned)xx < (unsigned)hi) csr[atomicAdd(&cur[xx], 1)] = p.y;
        xx = k.z - r0; if ((unsigned)xx < (unsigned)hi) csr[atomicAdd(&cur[xx], 1)] = p.z;
        xx = k.w - r0; if ((unsigned)xx < (unsigned)hi) csr[atomicAdd(&cur[xx], 1)] = p.w;
    }
}

// ---------------- coefficients ----------------

__global__ void finalize(const int* cntM, const int* cntS, const int* cnt0, const int* cnt1,
                         float* invCntM, float* invCntS,
                         float* dinv0, float* inv0, float* dinv1, float* inv1,
                         const float* __restrict__ sage_bl, const float* __restrict__ gcn_b,
                         float* bsum) {
    int i = blockIdx.x * blockDim.x + threadIdx.x;
    if (i < NM_N) {
        int c = cntM[i];
        invCntM[i] = 1.0f / (float)(c > 1 ? c : 1);
        float d0 = (float)cnt0[i] + 1.0f;
        dinv0[i] = 1.0f / sqrtf(d0);
        inv0[i] = 1.0f / d0;
        float d1 = (float)cnt1[i] + 1.0f;
        dinv1[i] = 1.0f / sqrtf(d1);
        inv1[i] = 1.0f / d1;
    }
    if (i < NS_N) {
        int c = cntS[i];
        invCntS[i] = 1.0f / (float)(c > 1 ? c : 1);
    }
    if (i < 256) {
        int l = i >> 7, c = i & 127;
        bsum[i] = sage_bl[(l * 2 + 0) * HD + c] + gcn_b[(l * 2 + 0) * HD + c] + gcn_b[(l * 2 + 1) * HD + c];
    }
}

// ---------------- fused fp32 -> bf16 conversions ----------------
// blocks [0,1600): emb_m; [1600,1920): emb_s; [1920,1932): weight transpose

__global__ __launch_bounds__(256) void conv_all(const float* __restrict__ emb_s,
                                                const float* __restrict__ emb_m,
                                                const float* __restrict__ sage_Wl,
                                                const float* __restrict__ sage_Wr,
                                                const float* __restrict__ gcn_W,
                                                unsigned short* __restrict__ emb_s16,
                                                unsigned short* __restrict__ emb_m16,
                                                unsigned short* __restrict__ Wt) {
    int b = blockIdx.x;
    if (b < 1920) {
        const float* src; unsigned short* dst; int n8; int i;
        if (b < 1600) { src = emb_m; dst = emb_m16; n8 = NM_N * HD / 8; i = b * 256 + threadIdx.x;
            for (; i < n8; i += 1600 * 256) {
                float4 v0 = ((const float4*)src)[(size_t)i * 2];
                float4 v1 = ((const float4*)src)[(size_t)i * 2 + 1];
                uint4 r;
                r.x = (unsigned int)f2bf(v0.x) | ((unsigned int)f2bf(v0.y) << 16);
                r.y = (unsigned int)f2bf(v0.z) | ((unsigned int)f2bf(v0.w) << 16);
                r.z = (unsigned int)f2bf(v1.x) | ((unsigned int)f2bf(v1.y) << 16);
                r.w = (unsigned int)f2bf(v1.z) | ((unsigned int)f2bf(v1.w) << 16);
                ((uint4*)dst)[i] = r;
            }
        } else { src = emb_s; dst = emb_s16; n8 = NS_N * HD / 8; i = (b - 1600) * 256 + threadIdx.x;
            for (; i < n8; i += 320 * 256) {
                float4 v0 = ((const float4*)src)[(size_t)i * 2];
                float4 v1 = ((const float4*)src)[(size_t)i * 2 + 1];
                uint4 r;
                r.x = (unsigned int)f2bf(v0.x) | ((unsigned int)f2bf(v0.y) << 16);
                r.y = (unsigned int)f2bf(v0.z) | ((unsigned int)f2bf(v0.w) << 16);
                r.z = (unsigned int)f2bf(v1.x) | ((unsigned int)f2bf(v1.y) << 16);
                r.w = (unsigned int)f2bf(v1.z) | ((unsigned int)f2bf(v1.w) << 16);
                ((uint4*)dst)[i] = r;
            }
        }
        return;
    }
    int o = b - 1920;
    int l = o / 6, m = o % 6;
    const float* src;
    switch (m) {
        case 0: src = sage_Wl + (size_t)(l * 2 + 0) * HD * HD; break;
        case 1: src = sage_Wr + (size_t)(l * 2 + 0) * HD * HD; break;
        case 2: src = gcn_W + (size_t)(l * 2 + 0) * HD * HD; break;
        case 3: src = gcn_W + (size_t)(l * 2 + 1) * HD * HD; break;
        case 4: src = sage_Wl + (size_t)(l * 2 + 1) * HD * HD; break;
        default: src = sage_Wr + (size_t)(l * 2 + 1) * HD * HD; break;
    }
    for (int it = 0; it < 64; it++) {
        int f = it * 256 + threadIdx.x;      // f = n*128 + k
        int n = f >> 7, k = f & 127;
        Wt[(size_t)o * 16384 + f] = f2bf(src[k * 128 + n]);
    }
}

// ---------------- fused gathers (bf16 rows, fp32 accum, 16 lanes/row) ----------------

__device__ inline void gath_mean(const unsigned short* __restrict__ x,
                                 const int* __restrict__ csr, const int* __restrict__ off,
                                 const int* __restrict__ cnt, const float* __restrict__ invc,
                                 unsigned short* __restrict__ out, int row, int lane) {
    int o = off[row], n = cnt[row];
    float a0=0,a1=0,a2=0,a3=0,a4=0,a5=0,a6=0,a7=0;
    int j = 0;
    for (; j + 2 <= n; j += 2) {
        int sa = csr[o + j], sb = csr[o + j + 1];
        uint4 va = *(const uint4*)(x + (size_t)sa * 128 + lane * 8);
        uint4 vb = *(const uint4*)(x + (size_t)sb * 128 + lane * 8);
        a0 += bf2f(va.x & 0xffffu) + bf2f(vb.x & 0xffffu);
        a1 += bf2f(va.x >> 16)     + bf2f(vb.x >> 16);
        a2 += bf2f(va.y & 0xffffu) + bf2f(vb.y & 0xffffu);
        a3 += bf2f(va.y >> 16)     + bf2f(vb.y >> 16);
        a4 += bf2f(va.z & 0xffffu) + bf2f(vb.z & 0xffffu);
        a5 += bf2f(va.z >> 16)     + bf2f(vb.z >> 16);
        a6 += bf2f(va.w & 0xffffu) + bf2f(vb.w & 0xffffu);
        a7 += bf2f(va.w >> 16)     + bf2f(vb.w >> 16);
    }
    if (j < n) {
        int sa = csr[o + j];
        uint4 v = *(const uint4*)(x + (size_t)sa * 128 + lane * 8);
        a0 += bf2f(v.x & 0xffffu); a1 += bf2f(v.x >> 16);
        a2 += bf2f(v.y & 0xffffu); a3 += bf2f(v.y >> 16);
        a4 += bf2f(v.z & 0xffffu); a5 += bf2f(v.z >> 16);
        a6 += bf2f(v.w & 0xffffu); a7 += bf2f(v.w >> 16);
    }
    float sc = invc[row];
    uint4 r;
    r.x = (unsigned int)f2bf(a0 * sc) | ((unsigned int)f2bf(a1 * sc) << 16);
    r.y = (unsigned int)f2bf(a2 * sc) | ((unsigned int)f2bf(a3 * sc) << 16);
    r.z = (unsigned int)f2bf(a4 * sc) | ((unsigned int)f2bf(a5 * sc) << 16);
    r.w = (unsigned int)f2bf(a6 * sc) | ((unsigned int)f2bf(a7 * sc) << 16);
    *(uint4*)(out + (size_t)row * 128 + lane * 8) = r;
}

__device__ inline void gath_gcn(const unsigned short* __restrict__ x,
                                const int* __restrict__ csr, const int* __restrict__ off,
                                const int* __restrict__ cnt, const float* __restrict__ dinv,
                                const float* __restrict__ invd,
                                unsigned short* __restrict__ out, int row, int lane) {
    int o = off[row], n = cnt[row];
    float a0=0,a1=0,a2=0,a3=0,a4=0,a5=0,a6=0,a7=0;
    int j = 0;
    for (; j + 2 <= n; j += 2) {
        int sa = csr[o + j], sb = csr[o + j + 1];
        float ca = dinv[sa], cb = dinv[sb];
        uint4 va = *(const uint4*)(x + (size_t)sa * 128 + lane * 8);
        uint4 vb = *(const uint4*)(x + (size_t)sb * 128 + lane * 8);
        a0 += ca * bf2f(va.x & 0xffffu) + cb * bf2f(vb.x & 0xffffu);
        a1 += ca * bf2f(va.x >> 16)     + cb * bf2f(vb.x >> 16);
        a2 += ca * bf2f(va.y & 0xffffu) + cb * bf2f(vb.y & 0xffffu);
        a3 += ca * bf2f(va.y >> 16)     + cb * bf2f(vb.y >> 16);
        a4 += ca * bf2f(va.z & 0xffffu) + cb * bf2f(vb.z & 0xffffu);
        a5 += ca * bf2f(va.z >> 16)     + cb * bf2f(vb.z >> 16);
        a6 += ca * bf2f(va.w & 0xffffu) + cb * bf2f(vb.w & 0xffffu);
        a7 += ca * bf2f(va.w >> 16)     + cb * bf2f(vb.w >> 16);
    }
    if (j < n) {
        int sa = csr[o + j];
        float ca = dinv[sa];
        uint4 v = *(const uint4*)(x + (size_t)sa * 128 + lane * 8);
        a0 += ca * bf2f(v.x & 0xffffu); a1 += ca * bf2f(v.x >> 16);
        a2 += ca * bf2f(v.y & 0xffffu); a3 += ca * bf2f(v.y >> 16);
        a4 += ca * bf2f(v.z & 0xffffu); a5 += ca * bf2f(v.z >> 16);
        a6 += ca * bf2f(v.w & 0xffffu); a7 += ca * bf2f(v.w >> 16);
    }
    float dr = dinv[row], iv = invd[row];
    uint4 sv = *(const uint4*)(x + (size_t)row * 128 + lane * 8);
    uint4 r;
    r.x = (unsigned int)f2bf(dr * a0 + iv * bf2f(sv.x & 0xffffu)) |
          ((unsigned int)f2bf(dr * a1 + iv * bf2f(sv.x >> 16)) << 16);
    r.y = (unsigned int)f2bf(dr * a2 + iv * bf2f(sv.y & 0xffffu)) |
          ((unsigned int)f2bf(dr * a3 + iv * bf2f(sv.y >> 16)) << 16);
    r.z = (unsigned int)f2bf(dr * a4 + iv * bf2f(sv.z & 0xffffu)) |
          ((unsigned int)f2bf(dr * a5 + iv * bf2f(sv.z >> 16)) << 16);
    r.w = (unsigned int)f2bf(dr * a6 + iv * bf2f(sv.w & 0xffffu)) |
          ((unsigned int)f2bf(dr * a7 + iv * bf2f(sv.w >> 16)) << 16);
    *(uint4*)(out + (size_t)row * 128 + lane * 8) = r;
}

// sections: [0,3125) A | [3125,3750) Sg | [3750,6875) B0 | [6875,10000) B1
__global__ __launch_bounds__(256) void gather_all(
        const unsigned short* __restrict__ xs, const unsigned short* __restrict__ xm,
        const int* __restrict__ csrA, const int* __restrict__ offM, const int* __restrict__ cntM,
        const float* __restrict__ invCntM,
        const int* __restrict__ csrS, const int* __restrict__ offS, const int* __restrict__ cntS,
        const float* __restrict__ invCntS,
        const int* __restrict__ csr0, const int* __restrict__ off0, const int* __restrict__ cnt0,
        const float* __restrict__ dinv0, const float* __restrict__ inv0,
        const int* __restrict__ csr1, const int* __restrict__ off1, const int* __restrict__ cnt1,
        const float* __restrict__ dinv1, const float* __restrict__ inv1,
        unsigned short* __restrict__ A, unsigned short* __restrict__ Sg,
        unsigned short* __restrict__ B0, unsigned short* __restrict__ B1) {
    int b = blockIdx.x;
    int sub = threadIdx.x >> 4, lane = threadIdx.x & 15;
    if (b < 3125) {
        int row = b * 16 + sub;
        if (row < NM_N) gath_mean(xs, csrA, offM, cntM, invCntM, A, row, lane);
    } else if (b < 3750) {
        int row = (b - 3125) * 16 + sub;
        if (row < NS_N) gath_mean(xm, csrS, offS, cntS, invCntS, Sg, row, lane);
    } else if (b < 6875) {
        int row = (b - 3750) * 16 + sub;
        if (row < NM_N) gath_gcn(xm, csr0, off0, cnt0, dinv0, inv0, B0, row, lane);
    } else {
        int row = (b - 6875) * 16 + sub;
        if (row < NM_N) gath_gcn(xm, csr1, off1, cnt1, dinv1, inv1, B1, row, lane);
    }
}

// ---------------- fused MFMA GEMM (M tiles + S tiles in one dispatch) ----------------

__global__ __launch_bounds__(256) void gemm_all(
        const unsigned short* __restrict__ A, const unsigned short* __restrict__ xm_cur,
        const unsigned short* __restrict__ B0, const unsigned short* __restrict__ B1,
        const unsigned short* __restrict__ Sg, const unsigned short* __restrict__ xs_cur,
        const unsigned short* __restrict__ Wt, const float* __restrict__ bsum,
        const float* __restrict__ sblS,
        unsigned short* __restrict__ xma, unsigned short* __restrict__ xsa, int l) {
    __shared__ unsigned short As[128 * 128];
    __shared__ unsigned short Ws[128 * 128];
    int bb = blockIdx.x;
    const unsigned short *in0, *in1, *in2, *in3, *W;
    const float* bias;
    unsigned short* out;
    int nrows, nseg, r0;
    if (bb < 391) {
        in0 = A; in1 = xm_cur; in2 = B0; in3 = B1;
        W = Wt + (size_t)(l * 6) * 16384;
        bias = bsum + l * 128; out = xma; nrows = NM_N; nseg = 4; r0 = bb * 128;
    } else {
        in0 = Sg; in1 = xs_cur; in2 = nullptr; in3 = nullptr;
        W = Wt + (size_t)(l * 6 + 4) * 16384;
        bias = sblS; out = xsa; nrows = NS_N; nseg = 2; r0 = (bb - 391) * 128;
    }
    int tid = threadIdx.x;
    int wid = tid >> 6, lane = tid & 63;
    int l16 = lane & 15, lhi = lane >> 4;
    int wr_ = (wid >> 1) * 64, wc_ = (wid & 1) * 64;
    f32x4 acc[4][4];
    #pragma unroll
    for (int i = 0; i < 4; i++)
        #pragma unroll
        for (int j = 0; j < 4; j++)
            acc[i][j] = (f32x4){0.f, 0.f, 0.f, 0.f};

    for (int s = 0; s < nseg; s++) {
        const unsigned short* in = (s == 0) ? in0 : (s == 1) ? in1 : (s == 2) ? in2 : in3;
        const unsigned short* Wp = W + (size_t)s * 16384;
        __syncthreads();
        #pragma unroll
        for (int it = 0; it < 8; it++) {
            int f = it * 256 + tid;
            int r = f >> 4, c = f & 15;
            int gr = r0 + r;
            uint4 v = {0u, 0u, 0u, 0u};
            if (gr < nrows) v = *(const uint4*)(in + (size_t)gr * 128 + c * 8);
            *(uint4*)&As[(size_t)(r * 16 + (c ^ (r & 7))) * 8] = v;
            uint4 wv = *(const uint4*)(Wp + (size_t)r * 128 + c * 8);
            *(uint4*)&Ws[(size_t)(r * 16 + (c ^ (r & 7))) * 8] = wv;
        }
        __syncthreads();
        #pragma unroll
        for (int ks = 0; ks < 4; ks++) {
            int kc = ks * 4 + lhi;
            bf16x8 a[4], bfr[4];
            #pragma unroll
            for (int i = 0; i < 4; i++) {
                int r = wr_ + i * 16 + l16;
                a[i] = *(const bf16x8*)&As[(size_t)(r * 16 + (kc ^ (r & 7))) * 8];
                int nn = wc_ + i * 16 + l16;
                bfr[i] = *(const bf16x8*)&Ws[(size_t)(nn * 16 + (kc ^ (nn & 7))) * 8];
            }
            #pragma unroll
            for (int i = 0; i < 4; i++)
                #pragma unroll
                for (int j = 0; j < 4; j++)
                    acc[i][j] = __builtin_amdgcn_mfma_f32_16x16x32_bf16(a[i], bfr[j], acc[i][j], 0, 0, 0);
        }
    }
    float bs[4];
    #pragma unroll
    for (int j = 0; j < 4; j++) bs[j] = bias[wc_ + j * 16 + l16];
    #pragma unroll
    for (int i = 0; i < 4; i++) {
        int rb = r0 + wr_ + i * 16 + lhi * 4;
        #pragma unroll
        for (int j = 0; j < 4; j++) {
            int cn = wc_ + j * 16 + l16;
            #pragma unroll
            for (int q = 0; q < 4; q++) {
                int r = rb + q;
                if (r < nrows) {
                    float v = acc[i][j][q] + bs[j];
                    out[(size_t)r * 128 + cn] = f2bf(fmaxf(v, 0.f));
                }
            }
        }
    }
}

// ---------------- classifier (16 lanes / pair) ----------------

__global__ __launch_bounds__(256) void classify16(
        const unsigned short* __restrict__ xs_, const unsigned short* __restrict__ xm_,
        const int* __restrict__ lsrc, const int* __restrict__ ldst,
        float* __restrict__ out) {
    int i = blockIdx.x * 16 + (threadIdx.x >> 4);
    if (i >= L_N) return;
    int lane = threadIdx.x & 15;
    int s = lsrc[i], d = ldst[i];
    uint4 a = *(const uint4*)(xs_ + (size_t)s * 128 + lane * 8);
    uint4 b = *(const uint4*)(xm_ + (size_t)d * 128 + lane * 8);
    float p = bf2f(a.x & 0xffffu) * bf2f(b.x & 0xffffu) + bf2f(a.x >> 16) * bf2f(b.x >> 16)
            + bf2f(a.y & 0xffffu) * bf2f(b.y & 0xffffu) + bf2f(a.y >> 16) * bf2f(b.y >> 16)
            + bf2f(a.z & 0xffffu) * bf2f(b.z & 0xffffu) + bf2f(a.z >> 16) * bf2f(b.z >> 16)
            + bf2f(a.w & 0xffffu) * bf2f(b.w & 0xffffu) + bf2f(a.w >> 16) * bf2f(b.w >> 16);
    #pragma unroll
    for (int o = 8; o > 0; o >>= 1) p += __shfl_xor(p, o);
    if (lane == 0) out[i] = p;
}

// ---------------- launch ----------------

extern "C" void kernel_launch(void* const* d_in, const int* in_sizes, int n_in,
                              void* d_out, int out_size, void* d_ws, size_t ws_size,
                              hipStream_t stream) {
    const float* emb_s   = (const float*)d_in[0];
    const float* emb_m   = (const float*)d_in[1];
    const float* sage_Wl = (const float*)d_in[2];
    const float* sage_bl = (const float*)d_in[3];
    const float* sage_Wr = (const float*)d_in[4];
    const float* gcn_W   = (const float*)d_in[5];
    const float* gcn_b   = (const float*)d_in[6];
    const int* e1s = (const int*)d_in[9];
    const int* e1d = (const int*)d_in[10];
    const int* e2s = (const int*)d_in[11];
    const int* e2d = (const int*)d_in[12];
    const int* ls  = (const int*)d_in[13];
    const int* ld  = (const int*)d_in[14];
    float* out = (float*)d_out;

    char* p = (char*)d_ws;
    auto alloc = [&](size_t bytes) -> void* {
        void* r = (void*)p;
        p += (bytes + 255) & ~(size_t)255;
        return r;
    };
    int* cntM = (int*)alloc((size_t)NM_N * 4);
    int* cntS = (int*)alloc((size_t)NS_N * 4);
    int* cnt0 = (int*)alloc((size_t)NM_N * 4);
    int* cnt1 = (int*)alloc((size_t)NM_N * 4);
    int* offM = (int*)alloc((size_t)NM_N * 4);
    int* offS = (int*)alloc((size_t)NS_N * 4);
    int* off0 = (int*)alloc((size_t)NM_N * 4);
    int* off1 = (int*)alloc((size_t)NM_N * 4);
    int* rangeTot  = (int*)alloc(NB_TOT * 4);
    int* rangeBase = (int*)alloc(NB_TOT * 4);
    float* invCntM = (float*)alloc((size_t)NM_N * 4);
    float* invCntS = (float*)alloc((size_t)NS_N * 4);
    float* dinv0 = (float*)alloc((size_t)NM_N * 4);
    float* inv0  = (float*)alloc((size_t)NM_N * 4);
    float* dinv1 = (float*)alloc((size_t)NM_N * 4);
    float* inv1  = (float*)alloc((size_t)NM_N * 4);
    float* bsum  = (float*)alloc(256 * 4);
    int* csrA = (int*)alloc((size_t)E1_N * 4);
    int* csrS = (int*)alloc((size_t)E1_N * 4);
    int* csr0 = (int*)alloc((size_t)E2_N * 4);
    int* csr1 = (int*)alloc((size_t)E2_N * 4);
    unsigned short* emb_s16 = (unsigned short*)alloc((size_t)NS_N * HD * 2);
    unsigned short* emb_m16 = (unsigned short*)alloc((size_t)NM_N * HD * 2);
    unsigned short* Wt  = (unsigned short*)alloc((size_t)12 * HD * HD * 2);
    unsigned short* A   = (unsigned short*)alloc((size_t)NM_N * HD * 2);
    unsigned short* B0  = (unsigned short*)alloc((size_t)NM_N * HD * 2);
    unsigned short* B1  = (unsigned short*)alloc((size_t)NM_N * HD * 2);
    unsigned short* Sg  = (unsigned short*)alloc((size_t)NS_N * HD * 2);
    unsigned short* xma = (unsigned short*)alloc((size_t)NM_N * HD * 2);
    unsigned short* xsa = (unsigned short*)alloc((size_t)NS_N * HD * 2);

    count_ranges<<<NB_TOT, 1024, 0, stream>>>(e1s, e1d, e2s, e2d,
                                              cntM, cntS, cnt0, cnt1, rangeTot);
    scan_ranges<<<1, 64, 0, stream>>>(rangeTot, rangeBase);
    place_ranges<<<NB_TOT, 1024, 0, stream>>>(e1s, e1d, e2s, e2d,
                                              cntM, cntS, cnt0, cnt1, rangeBase,
                                              offM, offS, off0, off1,
                                              csrA, csrS, csr0, csr1);
    finalize<<<(NM_N + 255) / 256, 256, 0, stream>>>(cntM, cntS, cnt0, cnt1,
                                                     invCntM, invCntS,
                                                     dinv0, inv0, dinv1, inv1,
                                                     sage_bl, gcn_b, bsum);
    conv_all<<<1932, 256, 0, stream>>>(emb_s, emb_m, sage_Wl, sage_Wr, gcn_W,
                                       emb_s16, emb_m16, Wt);

    for (int l = 0; l < 2; l++) {
        const unsigned short* xs_cur = l ? (const unsigned short*)xsa : emb_s16;
        const unsigned short* xm_cur = l ? (const unsigned short*)xma : emb_m16;
        gather_all<<<10000, 256, 0, stream>>>(xs_cur, xm_cur,
                                              csrA, offM, cntM, invCntM,
                                              csrS, offS, cntS, invCntS,
                                              csr0, off0, cnt0, dinv0, inv0,
                                              csr1, off1, cnt1, dinv1, inv1,
                                              A, Sg, B0, B1);
        gemm_all<<<470, 256, 0, stream>>>(A, xm_cur, B0, B1, Sg, xs_cur,
                                          Wt, bsum,
                                          sage_bl + (size_t)(l * 2 + 1) * HD,
                                          xma, xsa, l);
    }
    classify16<<<12500, 256, 0, stream>>>(xsa, xma, ls, ld, out);
}

// Round 7
// 396.027 us; speedup vs baseline: 2.9265x; 1.3669x over previous
//
#include <hip/hip_runtime.h>

#define NS_N 10000
#define NM_N 50000
#define HD 128
#define E1_N 600000
#define E2_N 400000
#define L_N 200000

#define RSZ 4096
#define NB_A 13
#define NB_S 3
#define NB_TOT 42
#define CHK 16

typedef short bf16x8 __attribute__((ext_vector_type(8)));
typedef float f32x4 __attribute__((ext_vector_type(4)));

__device__ inline float bf2f(unsigned int h) {
    union { unsigned int u; float f; } c; c.u = h << 16; return c.f;
}
__device__ inline unsigned short f2bf(float f) {
    union { float f; unsigned int u; } c; c.f = f;
    return (unsigned short)((c.u + 0x7fffu + ((c.u >> 16) & 1u)) >> 16);
}

// range table:  [0,13): csrA key=e1d payl=e1s (NM) | [13,16): csrS key=e1s payl=e1d (NS)
//               [16,29): csr0 key=e2d payl=e2s (NM) | [29,42): csr1 key=e2s payl=e2d (NM)

// ---------------- pass 1: per-(range,chunk) LDS histogram ----------------

__global__ __launch_bounds__(256) void count_chunks(
        const int* __restrict__ e1s, const int* __restrict__ e1d,
        const int* __restrict__ e2s, const int* __restrict__ e2d,
        int* __restrict__ subcnt, int* __restrict__ chunkTot) {
    __shared__ int hist[RSZ];
    __shared__ int wred[4];
    int b = blockIdx.x, tid = threadIdx.x;
    int rb = b / CHK, c = b % CHK;
    const int* keys; int ne; int nnode; int r0;
    if (rb < NB_A)             { keys = e1d; ne = E1_N; nnode = NM_N; r0 = rb * RSZ; }
    else if (rb < NB_A + NB_S) { keys = e1s; ne = E1_N; nnode = NS_N; r0 = (rb - NB_A) * RSZ; }
    else if (rb < 29)          { keys = e2d; ne = E2_N; nnode = NM_N; r0 = (rb - 16) * RSZ; }
    else                       { keys = e2s; ne = E2_N; nnode = NM_N; r0 = (rb - 29) * RSZ; }
    for (int i = tid; i < RSZ; i += 256) hist[i] = 0;
    __syncthreads();
    int hi = nnode - r0; if (hi > RSZ) hi = RSZ;
    const int4* k4 = (const int4*)keys;
    int ne4 = ne >> 2;
    int per = (ne4 + CHK - 1) / CHK;
    int i0 = c * per, i1 = i0 + per; if (i1 > ne4) i1 = ne4;
    for (int i = i0 + tid; i < i1; i += 256) {
        int4 v = k4[i];
        int x;
        x = v.x - r0; if ((unsigned)x < (unsigned)hi) atomicAdd(&hist[x], 1);
        x = v.y - r0; if ((unsigned)x < (unsigned)hi) atomicAdd(&hist[x], 1);
        x = v.z - r0; if ((unsigned)x < (unsigned)hi) atomicAdd(&hist[x], 1);
        x = v.w - r0; if ((unsigned)x < (unsigned)hi) atomicAdd(&hist[x], 1);
    }
    __syncthreads();
    int* sc = subcnt + (size_t)b * RSZ;
    int loc = 0;
    for (int i = tid; i < RSZ; i += 256) { int h = hist[i]; sc[i] = h; loc += h; }
    #pragma unroll
    for (int o = 32; o; o >>= 1) loc += __shfl_xor(loc, o);
    if ((tid & 63) == 0) wred[tid >> 6] = loc;
    __syncthreads();
    if (tid == 0) chunkTot[b] = wred[0] + wred[1] + wred[2] + wred[3];
}

// ---------------- pass 2: range bases from 672 chunk totals ----------------

__global__ void scan_ranges2(const int* __restrict__ chunkTot, int* __restrict__ rangeBase) {
    int t = threadIdx.x;
    if (t >= 4) return;
    const int s0[5] = {0, 13, 16, 29, 42};
    int acc = 0;
    for (int r = s0[t]; r < s0[t + 1]; r++) {
        rangeBase[r] = acc;
        int tot = 0;
        for (int c = 0; c < CHK; c++) tot += chunkTot[r * CHK + c];
        acc += tot;
    }
}

// ---------------- pass 3: per-range node scan; rewrite subcnt -> absolute chunk bases ----------------

__global__ __launch_bounds__(1024) void reduce_scan(
        const int* __restrict__ rangeBase,
        int* __restrict__ subcnt,
        int* cntM, int* cntS, int* cnt0, int* cnt1,
        int* offM, int* offS, int* off0, int* off1) {
    __shared__ int wsum[16];
    int rb = blockIdx.x, tid = threadIdx.x;
    int lane = tid & 63, w = tid >> 6;
    int* cnt; int* off; int nnode; int r0;
    if (rb < NB_A)             { cnt = cntM; off = offM; nnode = NM_N; r0 = rb * RSZ; }
    else if (rb < NB_A + NB_S) { cnt = cntS; off = offS; nnode = NS_N; r0 = (rb - NB_A) * RSZ; }
    else if (rb < 29)          { cnt = cnt0; off = off0; nnode = NM_N; r0 = (rb - 16) * RSZ; }
    else                       { cnt = cnt1; off = off1; nnode = NM_N; r0 = (rb - 29) * RSZ; }
    int hi = nnode - r0; if (hi > RSZ) hi = RSZ;
    int base = rangeBase[rb];
    int* sc0 = subcnt + (size_t)(rb * CHK) * RSZ;
    // per-node totals over chunks (4 nodes per thread)
    int cv[4]; int s = 0;
    #pragma unroll
    for (int q = 0; q < 4; q++) {
        int idx = tid * 4 + q;
        int t = 0;
        if (idx < hi)
            for (int c = 0; c < CHK; c++) t += sc0[(size_t)c * RSZ + idx];
        cv[q] = t; s += t;
    }
    int x = s;
    #pragma unroll
    for (int d = 1; d < 64; d <<= 1) { int y = __shfl_up(x, d); if (lane >= d) x += y; }
    if (lane == 63) wsum[w] = x;
    __syncthreads();
    if (w == 0 && lane < 16) {
        int y = wsum[lane];
        #pragma unroll
        for (int d = 1; d < 16; d <<= 1) { int z = __shfl_up(y, d); if (lane >= d) y += z; }
        wsum[lane] = y;
    }
    __syncthreads();
    int ebase = base + ((w > 0) ? wsum[w - 1] : 0) + (x - s);
    #pragma unroll
    for (int q = 0; q < 4; q++) {
        int idx = tid * 4 + q;
        if (idx < hi) {
            off[r0 + idx] = ebase;
            cnt[r0 + idx] = cv[q];
            int running = ebase;
            for (int c = 0; c < CHK; c++) {
                size_t a = (size_t)c * RSZ + idx;
                int tmp = sc0[a];
                sc0[a] = running;
                running += tmp;
            }
        }
        ebase += cv[q];
    }
}

// ---------------- pass 4: chunk scatter via precomputed bases ----------------

__global__ __launch_bounds__(256) void place_chunks(
        const int* __restrict__ e1s, const int* __restrict__ e1d,
        const int* __restrict__ e2s, const int* __restrict__ e2d,
        const int* __restrict__ subcnt,
        int* csrA, int* csrS, int* csr0, int* csr1) {
    __shared__ int cur[RSZ];
    int b = blockIdx.x, tid = threadIdx.x;
    int rb = b / CHK, c = b % CHK;
    const int* keys; const int* payl; int ne; int* csr; int nnode; int r0;
    if (rb < NB_A)             { keys = e1d; payl = e1s; ne = E1_N; csr = csrA; nnode = NM_N; r0 = rb * RSZ; }
    else if (rb < NB_A + NB_S) { keys = e1s; payl = e1d; ne = E1_N; csr = csrS; nnode = NS_N; r0 = (rb - NB_A) * RSZ; }
    else if (rb < 29)          { keys = e2d; payl = e2s; ne = E2_N; csr = csr0; nnode = NM_N; r0 = (rb - 16) * RSZ; }
    else                       { keys = e2s; payl = e2d; ne = E2_N; csr = csr1; nnode = NM_N; r0 = (rb - 29) * RSZ; }
    int hi = nnode - r0; if (hi > RSZ) hi = RSZ;
    const int* sc = subcnt + (size_t)b * RSZ;
    for (int i = tid; i < hi; i += 256) cur[i] = sc[i];
    __syncthreads();
    const int4* k4 = (const int4*)keys;
    const int4* p4 = (const int4*)payl;
    int ne4 = ne >> 2;
    int per = (ne4 + CHK - 1) / CHK;
    int i0 = c * per, i1 = i0 + per; if (i1 > ne4) i1 = ne4;
    for (int i = i0 + tid; i < i1; i += 256) {
        int4 k = k4[i]; int4 p = p4[i];
        int xx;
        xx = k.x - r0; if ((unsigned)xx < (unsigned)hi) csr[atomicAdd(&cur[xx], 1)] = p.x;
        xx = k.y - r0; if ((unsigned)xx < (unsigned)hi) csr[atomicAdd(&cur[xx], 1)] = p.y;
        xx = k.z - r0; if ((unsigned)xx < (unsigned)hi) csr[atomicAdd(&cur[xx], 1)] = p.z;
        xx = k.w - r0; if ((unsigned)xx < (unsigned)hi) csr[atomicAdd(&cur[xx], 1)] = p.w;
    }
}

// ---------------- coefficients ----------------

__global__ void finalize(const int* cntM, const int* cntS, const int* cnt0, const int* cnt1,
                         float* invCntM, float* invCntS,
                         float* dinv0, float* inv0, float* dinv1, float* inv1,
                         const float* __restrict__ sage_bl, const float* __restrict__ gcn_b,
                         float* bsum) {
    int i = blockIdx.x * blockDim.x + threadIdx.x;
    if (i < NM_N) {
        int c = cntM[i];
        invCntM[i] = 1.0f / (float)(c > 1 ? c : 1);
        float d0 = (float)cnt0[i] + 1.0f;
        dinv0[i] = 1.0f / sqrtf(d0);
        inv0[i] = 1.0f / d0;
        float d1 = (float)cnt1[i] + 1.0f;
        dinv1[i] = 1.0f / sqrtf(d1);
        inv1[i] = 1.0f / d1;
    }
    if (i < NS_N) {
        int c = cntS[i];
        invCntS[i] = 1.0f / (float)(c > 1 ? c : 1);
    }
    if (i < 256) {
        int l = i >> 7, c = i & 127;
        bsum[i] = sage_bl[(l * 2 + 0) * HD + c] + gcn_b[(l * 2 + 0) * HD + c] + gcn_b[(l * 2 + 1) * HD + c];
    }
}

// ---------------- fused fp32 -> bf16 conversions ----------------

__global__ __launch_bounds__(256) void conv_all(const float* __restrict__ emb_s,
                                                const float* __restrict__ emb_m,
                                                const float* __restrict__ sage_Wl,
                                                const float* __restrict__ sage_Wr,
                                                const float* __restrict__ gcn_W,
                                                unsigned short* __restrict__ emb_s16,
                                                unsigned short* __restrict__ emb_m16,
                                                unsigned short* __restrict__ Wt) {
    int b = blockIdx.x;
    if (b < 1920) {
        const float* src; unsigned short* dst; int n8; int i;
        if (b < 1600) { src = emb_m; dst = emb_m16; n8 = NM_N * HD / 8; i = b * 256 + threadIdx.x;
            for (; i < n8; i += 1600 * 256) {
                float4 v0 = ((const float4*)src)[(size_t)i * 2];
                float4 v1 = ((const float4*)src)[(size_t)i * 2 + 1];
                uint4 r;
                r.x = (unsigned int)f2bf(v0.x) | ((unsigned int)f2bf(v0.y) << 16);
                r.y = (unsigned int)f2bf(v0.z) | ((unsigned int)f2bf(v0.w) << 16);
                r.z = (unsigned int)f2bf(v1.x) | ((unsigned int)f2bf(v1.y) << 16);
                r.w = (unsigned int)f2bf(v1.z) | ((unsigned int)f2bf(v1.w) << 16);
                ((uint4*)dst)[i] = r;
            }
        } else { src = emb_s; dst = emb_s16; n8 = NS_N * HD / 8; i = (b - 1600) * 256 + threadIdx.x;
            for (; i < n8; i += 320 * 256) {
                float4 v0 = ((const float4*)src)[(size_t)i * 2];
                float4 v1 = ((const float4*)src)[(size_t)i * 2 + 1];
                uint4 r;
                r.x = (unsigned int)f2bf(v0.x) | ((unsigned int)f2bf(v0.y) << 16);
                r.y = (unsigned int)f2bf(v0.z) | ((unsigned int)f2bf(v0.w) << 16);
                r.z = (unsigned int)f2bf(v1.x) | ((unsigned int)f2bf(v1.y) << 16);
                r.w = (unsigned int)f2bf(v1.z) | ((unsigned int)f2bf(v1.w) << 16);
                ((uint4*)dst)[i] = r;
            }
        }
        return;
    }
    int o = b - 1920;
    int l = o / 6, m = o % 6;
    const float* src;
    switch (m) {
        case 0: src = sage_Wl + (size_t)(l * 2 + 0) * HD * HD; break;
        case 1: src = sage_Wr + (size_t)(l * 2 + 0) * HD * HD; break;
        case 2: src = gcn_W + (size_t)(l * 2 + 0) * HD * HD; break;
        case 3: src = gcn_W + (size_t)(l * 2 + 1) * HD * HD; break;
        case 4: src = sage_Wl + (size_t)(l * 2 + 1) * HD * HD; break;
        default: src = sage_Wr + (size_t)(l * 2 + 1) * HD * HD; break;
    }
    for (int it = 0; it < 64; it++) {
        int f = it * 256 + threadIdx.x;      // f = n*128 + k
        int n = f >> 7, k = f & 127;
        Wt[(size_t)o * 16384 + f] = f2bf(src[k * 128 + n]);
    }
}

// ---------------- fused gathers (bf16 rows, fp32 accum, 16 lanes/row) ----------------

__device__ inline void gath_mean(const unsigned short* __restrict__ x,
                                 const int* __restrict__ csr, const int* __restrict__ off,
                                 const int* __restrict__ cnt, const float* __restrict__ invc,
                                 unsigned short* __restrict__ out, int row, int lane) {
    int o = off[row], n = cnt[row];
    float a0=0,a1=0,a2=0,a3=0,a4=0,a5=0,a6=0,a7=0;
    int j = 0;
    for (; j + 2 <= n; j += 2) {
        int sa = csr[o + j], sb = csr[o + j + 1];
        uint4 va = *(const uint4*)(x + (size_t)sa * 128 + lane * 8);
        uint4 vb = *(const uint4*)(x + (size_t)sb * 128 + lane * 8);
        a0 += bf2f(va.x & 0xffffu) + bf2f(vb.x & 0xffffu);
        a1 += bf2f(va.x >> 16)     + bf2f(vb.x >> 16);
        a2 += bf2f(va.y & 0xffffu) + bf2f(vb.y & 0xffffu);
        a3 += bf2f(va.y >> 16)     + bf2f(vb.y >> 16);
        a4 += bf2f(va.z & 0xffffu) + bf2f(vb.z & 0xffffu);
        a5 += bf2f(va.z >> 16)     + bf2f(vb.z >> 16);
        a6 += bf2f(va.w & 0xffffu) + bf2f(vb.w & 0xffffu);
        a7 += bf2f(va.w >> 16)     + bf2f(vb.w >> 16);
    }
    if (j < n) {
        int sa = csr[o + j];
        uint4 v = *(const uint4*)(x + (size_t)sa * 128 + lane * 8);
        a0 += bf2f(v.x & 0xffffu); a1 += bf2f(v.x >> 16);
        a2 += bf2f(v.y & 0xffffu); a3 += bf2f(v.y >> 16);
        a4 += bf2f(v.z & 0xffffu); a5 += bf2f(v.z >> 16);
        a6 += bf2f(v.w & 0xffffu); a7 += bf2f(v.w >> 16);
    }
    float sc = invc[row];
    uint4 r;
    r.x = (unsigned int)f2bf(a0 * sc) | ((unsigned int)f2bf(a1 * sc) << 16);
    r.y = (unsigned int)f2bf(a2 * sc) | ((unsigned int)f2bf(a3 * sc) << 16);
    r.z = (unsigned int)f2bf(a4 * sc) | ((unsigned int)f2bf(a5 * sc) << 16);
    r.w = (unsigned int)f2bf(a6 * sc) | ((unsigned int)f2bf(a7 * sc) << 16);
    *(uint4*)(out + (size_t)row * 128 + lane * 8) = r;
}

__device__ inline void gath_gcn(const unsigned short* __restrict__ x,
                                const int* __restrict__ csr, const int* __restrict__ off,
                                const int* __restrict__ cnt, const float* __restrict__ dinv,
                                const float* __restrict__ invd,
                                unsigned short* __restrict__ out, int row, int lane) {
    int o = off[row], n = cnt[row];
    float a0=0,a1=0,a2=0,a3=0,a4=0,a5=0,a6=0,a7=0;
    int j = 0;
    for (; j + 2 <= n; j += 2) {
        int sa = csr[o + j], sb = csr[o + j + 1];
        float ca = dinv[sa], cb = dinv[sb];
        uint4 va = *(const uint4*)(x + (size_t)sa * 128 + lane * 8);
        uint4 vb = *(const uint4*)(x + (size_t)sb * 128 + lane * 8);
        a0 += ca * bf2f(va.x & 0xffffu) + cb * bf2f(vb.x & 0xffffu);
        a1 += ca * bf2f(va.x >> 16)     + cb * bf2f(vb.x >> 16);
        a2 += ca * bf2f(va.y & 0xffffu) + cb * bf2f(vb.y & 0xffffu);
        a3 += ca * bf2f(va.y >> 16)     + cb * bf2f(vb.y >> 16);
        a4 += ca * bf2f(va.z & 0xffffu) + cb * bf2f(vb.z & 0xffffu);
        a5 += ca * bf2f(va.z >> 16)     + cb * bf2f(vb.z >> 16);
        a6 += ca * bf2f(va.w & 0xffffu) + cb * bf2f(vb.w & 0xffffu);
        a7 += ca * bf2f(va.w >> 16)     + cb * bf2f(vb.w >> 16);
    }
    if (j < n) {
        int sa = csr[o + j];
        float ca = dinv[sa];
        uint4 v = *(const uint4*)(x + (size_t)sa * 128 + lane * 8);
        a0 += ca * bf2f(v.x & 0xffffu); a1 += ca * bf2f(v.x >> 16);
        a2 += ca * bf2f(v.y & 0xffffu); a3 += ca * bf2f(v.y >> 16);
        a4 += ca * bf2f(v.z & 0xffffu); a5 += ca * bf2f(v.z >> 16);
        a6 += ca * bf2f(v.w & 0xffffu); a7 += ca * bf2f(v.w >> 16);
    }
    float dr = dinv[row], iv = invd[row];
    uint4 sv = *(const uint4*)(x + (size_t)row * 128 + lane * 8);
    uint4 r;
    r.x = (unsigned int)f2bf(dr * a0 + iv * bf2f(sv.x & 0xffffu)) |
          ((unsigned int)f2bf(dr * a1 + iv * bf2f(sv.x >> 16)) << 16);
    r.y = (unsigned int)f2bf(dr * a2 + iv * bf2f(sv.y & 0xffffu)) |
          ((unsigned int)f2bf(dr * a3 + iv * bf2f(sv.y >> 16)) << 16);
    r.z = (unsigned int)f2bf(dr * a4 + iv * bf2f(sv.z & 0xffffu)) |
          ((unsigned int)f2bf(dr * a5 + iv * bf2f(sv.z >> 16)) << 16);
    r.w = (unsigned int)f2bf(dr * a6 + iv * bf2f(sv.w & 0xffffu)) |
          ((unsigned int)f2bf(dr * a7 + iv * bf2f(sv.w >> 16)) << 16);
    *(uint4*)(out + (size_t)row * 128 + lane * 8) = r;
}

// sections: [0,3125) A | [3125,3750) Sg | [3750,6875) B0 | [6875,10000) B1
__global__ __launch_bounds__(256) void gather_all(
        const unsigned short* __restrict__ xs, const unsigned short* __restrict__ xm,
        const int* __restrict__ csrA, const int* __restrict__ offM, const int* __restrict__ cntM,
        const float* __restrict__ invCntM,
        const int* __restrict__ csrS, const int* __restrict__ offS, const int* __restrict__ cntS,
        const float* __restrict__ invCntS,
        const int* __restrict__ csr0, const int* __restrict__ off0, const int* __restrict__ cnt0,
        const float* __restrict__ dinv0, const float* __restrict__ inv0,
        const int* __restrict__ csr1, const int* __restrict__ off1, const int* __restrict__ cnt1,
        const float* __restrict__ dinv1, const float* __restrict__ inv1,
        unsigned short* __restrict__ A, unsigned short* __restrict__ Sg,
        unsigned short* __restrict__ B0, unsigned short* __restrict__ B1) {
    int b = blockIdx.x;
    int sub = threadIdx.x >> 4, lane = threadIdx.x & 15;
    if (b < 3125) {
        int row = b * 16 + sub;
        if (row < NM_N) gath_mean(xs, csrA, offM, cntM, invCntM, A, row, lane);
    } else if (b < 3750) {
        int row = (b - 3125) * 16 + sub;
        if (row < NS_N) gath_mean(xm, csrS, offS, cntS, invCntS, Sg, row, lane);
    } else if (b < 6875) {
        int row = (b - 3750) * 16 + sub;
        if (row < NM_N) gath_gcn(xm, csr0, off0, cnt0, dinv0, inv0, B0, row, lane);
    } else {
        int row = (b - 6875) * 16 + sub;
        if (row < NM_N) gath_gcn(xm, csr1, off1, cnt1, dinv1, inv1, B1, row, lane);
    }
}

// ---------------- fused MFMA GEMM (M tiles + S tiles in one dispatch) ----------------

__global__ __launch_bounds__(256) void gemm_all(
        const unsigned short* __restrict__ A, const unsigned short* __restrict__ xm_cur,
        const unsigned short* __restrict__ B0, const unsigned short* __restrict__ B1,
        const unsigned short* __restrict__ Sg, const unsigned short* __restrict__ xs_cur,
        const unsigned short* __restrict__ Wt, const float* __restrict__ bsum,
        const float* __restrict__ sblS,
        unsigned short* __restrict__ xma, unsigned short* __restrict__ xsa, int l) {
    __shared__ unsigned short As[128 * 128];
    __shared__ unsigned short Ws[128 * 128];
    int bb = blockIdx.x;
    const unsigned short *in0, *in1, *in2, *in3, *W;
    const float* bias;
    unsigned short* out;
    int nrows, nseg, r0;
    if (bb < 391) {
        in0 = A; in1 = xm_cur; in2 = B0; in3 = B1;
        W = Wt + (size_t)(l * 6) * 16384;
        bias = bsum + l * 128; out = xma; nrows = NM_N; nseg = 4; r0 = bb * 128;
    } else {
        in0 = Sg; in1 = xs_cur; in2 = nullptr; in3 = nullptr;
        W = Wt + (size_t)(l * 6 + 4) * 16384;
        bias = sblS; out = xsa; nrows = NS_N; nseg = 2; r0 = (bb - 391) * 128;
    }
    int tid = threadIdx.x;
    int wid = tid >> 6, lane = tid & 63;
    int l16 = lane & 15, lhi = lane >> 4;
    int wr_ = (wid >> 1) * 64, wc_ = (wid & 1) * 64;
    f32x4 acc[4][4];
    #pragma unroll
    for (int i = 0; i < 4; i++)
        #pragma unroll
        for (int j = 0; j < 4; j++)
            acc[i][j] = (f32x4){0.f, 0.f, 0.f, 0.f};

    for (int s = 0; s < nseg; s++) {
        const unsigned short* in = (s == 0) ? in0 : (s == 1) ? in1 : (s == 2) ? in2 : in3;
        const unsigned short* Wp = W + (size_t)s * 16384;
        __syncthreads();
        #pragma unroll
        for (int it = 0; it < 8; it++) {
            int f = it * 256 + tid;
            int r = f >> 4, c = f & 15;
            int gr = r0 + r;
            uint4 v = {0u, 0u, 0u, 0u};
            if (gr < nrows) v = *(const uint4*)(in + (size_t)gr * 128 + c * 8);
            *(uint4*)&As[(size_t)(r * 16 + (c ^ (r & 7))) * 8] = v;
            uint4 wv = *(const uint4*)(Wp + (size_t)r * 128 + c * 8);
            *(uint4*)&Ws[(size_t)(r * 16 + (c ^ (r & 7))) * 8] = wv;
        }
        __syncthreads();
        #pragma unroll
        for (int ks = 0; ks < 4; ks++) {
            int kc = ks * 4 + lhi;
            bf16x8 a[4], bfr[4];
            #pragma unroll
            for (int i = 0; i < 4; i++) {
                int r = wr_ + i * 16 + l16;
                a[i] = *(const bf16x8*)&As[(size_t)(r * 16 + (kc ^ (r & 7))) * 8];
                int nn = wc_ + i * 16 + l16;
                bfr[i] = *(const bf16x8*)&Ws[(size_t)(nn * 16 + (kc ^ (nn & 7))) * 8];
            }
            #pragma unroll
            for (int i = 0; i < 4; i++)
                #pragma unroll
                for (int j = 0; j < 4; j++)
                    acc[i][j] = __builtin_amdgcn_mfma_f32_16x16x32_bf16(a[i], bfr[j], acc[i][j], 0, 0, 0);
        }
    }
    float bs[4];
    #pragma unroll
    for (int j = 0; j < 4; j++) bs[j] = bias[wc_ + j * 16 + l16];
    #pragma unroll
    for (int i = 0; i < 4; i++) {
        int rb = r0 + wr_ + i * 16 + lhi * 4;
        #pragma unroll
        for (int j = 0; j < 4; j++) {
            int cn = wc_ + j * 16 + l16;
            #pragma unroll
            for (int q = 0; q < 4; q++) {
                int r = rb + q;
                if (r < nrows) {
                    float v = acc[i][j][q] + bs[j];
                    out[(size_t)r * 128 + cn] = f2bf(fmaxf(v, 0.f));
                }
            }
        }
    }
}

// ---------------- classifier (16 lanes / pair) ----------------

__global__ __launch_bounds__(256) void classify16(
        const unsigned short* __restrict__ xs_, const unsigned short* __restrict__ xm_,
        const int* __restrict__ lsrc, const int* __restrict__ ldst,
        float* __restrict__ out) {
    int i = blockIdx.x * 16 + (threadIdx.x >> 4);
    if (i >= L_N) return;
    int lane = threadIdx.x & 15;
    int s = lsrc[i], d = ldst[i];
    uint4 a = *(const uint4*)(xs_ + (size_t)s * 128 + lane * 8);
    uint4 b = *(const uint4*)(xm_ + (size_t)d * 128 + lane * 8);
    float p = bf2f(a.x & 0xffffu) * bf2f(b.x & 0xffffu) + bf2f(a.x >> 16) * bf2f(b.x >> 16)
            + bf2f(a.y & 0xffffu) * bf2f(b.y & 0xffffu) + bf2f(a.y >> 16) * bf2f(b.y >> 16)
            + bf2f(a.z & 0xffffu) * bf2f(b.z & 0xffffu) + bf2f(a.z >> 16) * bf2f(b.z >> 16)
            + bf2f(a.w & 0xffffu) * bf2f(b.w & 0xffffu) + bf2f(a.w >> 16) * bf2f(b.w >> 16);
    #pragma unroll
    for (int o = 8; o > 0; o >>= 1) p += __shfl_xor(p, o);
    if (lane == 0) out[i] = p;
}

// ---------------- launch ----------------

extern "C" void kernel_launch(void* const* d_in, const int* in_sizes, int n_in,
                              void* d_out, int out_size, void* d_ws, size_t ws_size,
                              hipStream_t stream) {
    const float* emb_s   = (const float*)d_in[0];
    const float* emb_m   = (const float*)d_in[1];
    const float* sage_Wl = (const float*)d_in[2];
    const float* sage_bl = (const float*)d_in[3];
    const float* sage_Wr = (const float*)d_in[4];
    const float* gcn_W   = (const float*)d_in[5];
    const float* gcn_b   = (const float*)d_in[6];
    const int* e1s = (const int*)d_in[9];
    const int* e1d = (const int*)d_in[10];
    const int* e2s = (const int*)d_in[11];
    const int* e2d = (const int*)d_in[12];
    const int* ls  = (const int*)d_in[13];
    const int* ld  = (const int*)d_in[14];
    float* out = (float*)d_out;

    char* p = (char*)d_ws;
    auto alloc = [&](size_t bytes) -> void* {
        void* r = (void*)p;
        p += (bytes + 255) & ~(size_t)255;
        return r;
    };
    int* cntM = (int*)alloc((size_t)NM_N * 4);
    int* cntS = (int*)alloc((size_t)NS_N * 4);
    int* cnt0 = (int*)alloc((size_t)NM_N * 4);
    int* cnt1 = (int*)alloc((size_t)NM_N * 4);
    int* offM = (int*)alloc((size_t)NM_N * 4);
    int* offS = (int*)alloc((size_t)NS_N * 4);
    int* off0 = (int*)alloc((size_t)NM_N * 4);
    int* off1 = (int*)alloc((size_t)NM_N * 4);
    int* subcnt   = (int*)alloc((size_t)NB_TOT * CHK * RSZ * 4);
    int* chunkTot = (int*)alloc((size_t)NB_TOT * CHK * 4);
    int* rangeBase = (int*)alloc(NB_TOT * 4);
    float* invCntM = (float*)alloc((size_t)NM_N * 4);
    float* invCntS = (float*)alloc((size_t)NS_N * 4);
    float* dinv0 = (float*)alloc((size_t)NM_N * 4);
    float* inv0  = (float*)alloc((size_t)NM_N * 4);
    float* dinv1 = (float*)alloc((size_t)NM_N * 4);
    float* inv1  = (float*)alloc((size_t)NM_N * 4);
    float* bsum  = (float*)alloc(256 * 4);
    int* csrA = (int*)alloc((size_t)E1_N * 4);
    int* csrS = (int*)alloc((size_t)E1_N * 4);
    int* csr0 = (int*)alloc((size_t)E2_N * 4);
    int* csr1 = (int*)alloc((size_t)E2_N * 4);
    unsigned short* emb_s16 = (unsigned short*)alloc((size_t)NS_N * HD * 2);
    unsigned short* emb_m16 = (unsigned short*)alloc((size_t)NM_N * HD * 2);
    unsigned short* Wt  = (unsigned short*)alloc((size_t)12 * HD * HD * 2);
    unsigned short* A   = (unsigned short*)alloc((size_t)NM_N * HD * 2);
    unsigned short* B0  = (unsigned short*)alloc((size_t)NM_N * HD * 2);
    unsigned short* B1  = (unsigned short*)alloc((size_t)NM_N * HD * 2);
    unsigned short* Sg  = (unsigned short*)alloc((size_t)NS_N * HD * 2);
    unsigned short* xma = (unsigned short*)alloc((size_t)NM_N * HD * 2);
    unsigned short* xsa = (unsigned short*)alloc((size_t)NS_N * HD * 2);

    count_chunks<<<NB_TOT * CHK, 256, 0, stream>>>(e1s, e1d, e2s, e2d, subcnt, chunkTot);
    scan_ranges2<<<1, 64, 0, stream>>>(chunkTot, rangeBase);
    reduce_scan<<<NB_TOT, 1024, 0, stream>>>(rangeBase, subcnt,
                                             cntM, cntS, cnt0, cnt1,
                                             offM, offS, off0, off1);
    place_chunks<<<NB_TOT * CHK, 256, 0, stream>>>(e1s, e1d, e2s, e2d, subcnt,
                                                   csrA, csrS, csr0, csr1);
    finalize<<<(NM_N + 255) / 256, 256, 0, stream>>>(cntM, cntS, cnt0, cnt1,
                                                     invCntM, invCntS,
                                                     dinv0, inv0, dinv1, inv1,
                                                     sage_bl, gcn_b, bsum);
    conv_all<<<1932, 256, 0, stream>>>(emb_s, emb_m, sage_Wl, sage_Wr, gcn_W,
                                       emb_s16, emb_m16, Wt);

    for (int l = 0; l < 2; l++) {
        const unsigned short* xs_cur = l ? (const unsigned short*)xsa : emb_s16;
        const unsigned short* xm_cur = l ? (const unsigned short*)xma : emb_m16;
        gather_all<<<10000, 256, 0, stream>>>(xs_cur, xm_cur,
                                              csrA, offM, cntM, invCntM,
                                              csrS, offS, cntS, invCntS,
                                              csr0, off0, cnt0, dinv0, inv0,
                                              csr1, off1, cnt1, dinv1, inv1,
                                              A, Sg, B0, B1);
        gemm_all<<<470, 256, 0, stream>>>(A, xm_cur, B0, B1, Sg, xs_cur,
                                          Wt, bsum,
                                          sage_bl + (size_t)(l * 2 + 1) * HD,
                                          xma, xsa, l);
    }
    classify16<<<12500, 256, 0, stream>>>(xsa, xma, ls, ld, out);
}